// Round 11
// baseline (266.713 us; speedup 1.0000x reference)
//
#include <hip/hip_runtime.h>
#include <hip/hip_bf16.h>
#include <math.h>

#define M_TOT 8192
#define D_DIM 1024
#define E_NUM 8
#define P_DIM 1024
#define K_TOT (E_NUM * D_DIM)  // 8192

typedef __attribute__((ext_vector_type(8))) short short8;
typedef __attribute__((ext_vector_type(4))) float f32x4;
typedef __attribute__((ext_vector_type(8))) unsigned short u16x8;

// round-to-nearest-even f32 -> bf16 (finite inputs)
static __device__ __forceinline__ unsigned short f2bf(float f) {
  unsigned u = __builtin_bit_cast(unsigned, f);
  unsigned r = (u + 0x7fffu + ((u >> 16) & 1u)) >> 16;
  return (unsigned short)r;
}

// ---- fused gate+xb: softmax(x@gw+gb) -> gate[M,E]; xb[m][d]=bf16(x) swizzled per 64-short block ----
__global__ __launch_bounds__(256) void gate_xb_kernel(const float* __restrict__ x,
                                                      const float* __restrict__ gw,
                                                      const float* __restrict__ gb,
                                                      float* __restrict__ gate,
                                                      unsigned short* __restrict__ xb) {
  const int row  = blockIdx.x * 4 + (threadIdx.x >> 6);
  const int lane = threadIdx.x & 63;
  const float* xr = x + (size_t)row * D_DIM + lane * 16;
  float xx[16];
#pragma unroll
  for (int q = 0; q < 4; ++q) {
    const float4 v = reinterpret_cast<const float4*>(xr)[q];
    xx[q * 4 + 0] = v.x; xx[q * 4 + 1] = v.y; xx[q * 4 + 2] = v.z; xx[q * 4 + 3] = v.w;
  }
  float acc[E_NUM];
#pragma unroll
  for (int e = 0; e < E_NUM; ++e) acc[e] = 0.f;
#pragma unroll
  for (int j = 0; j < 16; ++j) {
    const int d = lane * 16 + j;
    const float4* g4 = reinterpret_cast<const float4*>(gw + (size_t)d * E_NUM);
    const float4 a = g4[0], b = g4[1];
    const float xv = xx[j];
    acc[0] += xv * a.x; acc[1] += xv * a.y; acc[2] += xv * a.z; acc[3] += xv * a.w;
    acc[4] += xv * b.x; acc[5] += xv * b.y; acc[6] += xv * b.z; acc[7] += xv * b.w;
  }
#pragma unroll
  for (int off = 32; off >= 1; off >>= 1) {
#pragma unroll
    for (int e = 0; e < E_NUM; ++e) acc[e] += __shfl_xor(acc[e], off, 64);
  }
  if (lane == 0) {
    float v[E_NUM], mx = -1e30f;
#pragma unroll
    for (int e = 0; e < E_NUM; ++e) { v[e] = acc[e] + gb[e]; mx = fmaxf(mx, v[e]); }
    float s = 0.f;
#pragma unroll
    for (int e = 0; e < E_NUM; ++e) { v[e] = expf(v[e] - mx); s += v[e]; }
    const float inv = 1.f / s;
#pragma unroll
    for (int e = 0; e < E_NUM; ++e) gate[(size_t)row * E_NUM + e] = v[e] * inv;
  }
  // xb: two swizzled 16B chunks per lane
  unsigned short* xrow = xb + (size_t)row * D_DIM;
#pragma unroll
  for (int h = 0; h < 2; ++h) {
    const int jd = lane * 2 + h;
    const int cbase = (jd >> 3) * 8 + ((jd & 7) ^ (row & 7));
    u16x8 v;
#pragma unroll
    for (int k = 0; k < 8; ++k) v[k] = f2bf(xx[h * 8 + k]);
    *reinterpret_cast<u16x8*>(&xrow[cbase * 8]) = v;
  }
}

// ---------------- W [E][D][P] f32 -> wt [P][E*D] bf16, swizzle baked per 64-short K-block ----------------
__global__ __launch_bounds__(256) void wtrans2_kernel(const float* __restrict__ w,
                                                      unsigned short* __restrict__ wt) {
  __shared__ float tile[64][65];
  const int e  = blockIdx.z;
  const int p0 = blockIdx.y * 64;
  const int d0 = blockIdx.x * 64;
  const int tx = threadIdx.x & 63;
  const int ty = threadIdx.x >> 6;
  const float* src = w + ((size_t)e * D_DIM + d0) * P_DIM + p0;
#pragma unroll
  for (int i = 0; i < 16; ++i) {
    const int dr = i * 4 + ty;
    tile[dr][tx] = src[(size_t)dr * P_DIM + tx];
  }
  __syncthreads();
#pragma unroll
  for (int i = 0; i < 16; ++i) {
    const int pr = i * 4 + ty;
    const int c = tx ^ ((pr & 7) << 3);  // involution, 16B-chunk granular
    wt[(size_t)(p0 + pr) * K_TOT + e * D_DIM + d0 + c] = f2bf(tile[tx][pr]);
  }
}

// ---------------- out[m][p] = sum_e gate[m,e]*eb[e,p]  (replaces memset; gemm atomically adds) ----------------
__global__ __launch_bounds__(256) void biasinit_kernel(const float* __restrict__ gate,
                                                       const float* __restrict__ eb,
                                                       float* __restrict__ out) {
  const int m = blockIdx.x;
  const int p = threadIdx.x * 4;
  const float* g = gate + (size_t)m * E_NUM;
  float4 s = {0.f, 0.f, 0.f, 0.f};
#pragma unroll
  for (int e = 0; e < E_NUM; ++e) {
    const float ge = g[e];
    const float4 b4 = *reinterpret_cast<const float4*>(&eb[(size_t)e * P_DIM + p]);
    s.x += ge * b4.x; s.y += ge * b4.y; s.z += ge * b4.z; s.w += ge * b4.w;
  }
  *reinterpret_cast<float4*>(&out[(size_t)m * P_DIM + p]) = s;
}

// ---- split-K=4 Horner GEMM: 128x128 tile, BK=64, 4 waves, 32KB LDS -> 5 blocks/CU eligible ----
// Block (mt, nt, kq): kq owns experts {2kq, 2kq+1}; Horner rescale between them; final scale g[2kq+1].
__global__ __launch_bounds__(256, 5) void gemm_sk4_kernel(
    const unsigned short* __restrict__ xb,
    const unsigned short* __restrict__ wt,
    const float* __restrict__ gate,
    float* __restrict__ out) {
  __shared__ unsigned short lA[128 * 64];   // 16 KB
  __shared__ unsigned short lB[128 * 64];   // 16 KB  -> 32 KB total

  const int tid  = threadIdx.x;
  const int lane = tid & 63;
  const int wid  = tid >> 6;
  const int wr   = wid >> 1, wc = wid & 1;

  // 2048 blocks: xcd = nt (wt slice 2MB L2-resident); idx: kq = idx&3, mt = idx>>2.
  // kq siblings (same mt,nt) share the XCD -> atomic adds L2-local.
  const int bid = blockIdx.x;
  const int nt  = bid & 7;
  const int idx = bid >> 3;
  const int kq  = idx & 3;
  const int mt  = idx >> 2;
  const int m0  = mt * 128, n0 = nt * 128;
  const int e0x = kq * 2;

  f32x4 acc[4][4];
#pragma unroll
  for (int i = 0; i < 4; ++i)
#pragma unroll
    for (int j = 0; j < 4; ++j)
#pragma unroll
      for (int k = 0; k < 4; ++k) acc[i][j][k] = 0.f;

  const int r0 = tid >> 3;  // 0..31
  const int c8 = tid & 7;   // 16B chunk within 64-short block
  const unsigned short* pAb = xb + (size_t)(m0 + r0) * D_DIM + c8 * 8;
  const unsigned short* pBb = wt + (size_t)(n0 + r0) * K_TOT + (size_t)e0x * D_DIM + c8 * 8;

  float gl[16];  // final per-row gate scale g[row][e0x+1] (filled during rescale / first pass)

  for (int e = 0; e < 2; ++e) {
    if (e == 1) {
      // Horner rescale: acc *= g[row][e0x] / g[row][e0x+1]; cache g[row][e0x+1]
#pragma unroll
      for (int m = 0; m < 4; ++m) {
#pragma unroll
        for (int reg = 0; reg < 4; ++reg) {
          const int r = wr * 64 + m * 16 + (lane >> 4) * 4 + reg;
          const float2 gp = *reinterpret_cast<const float2*>(&gate[(size_t)(m0 + r) * E_NUM + e0x]);
          gl[m * 4 + reg] = gp.y;
          const float ratio = gp.x / gp.y;
#pragma unroll
          for (int n = 0; n < 4; ++n) acc[m][n][reg] *= ratio;
        }
      }
    }
    const unsigned short* pB = pBb + (size_t)e * D_DIM;
    for (int kt = 0; kt < 16; ++kt) {
      __syncthreads();  // previous tile's LDS reads complete
#pragma unroll
      for (int i = 0; i < 4; ++i) {
        __builtin_amdgcn_global_load_lds(
            (const __attribute__((address_space(1))) void*)(pAb + (size_t)i * 32 * D_DIM + kt * 64),
            (__attribute__((address_space(3))) void*)&lA[(tid + i * 256) * 8], 16, 0, 0);
      }
#pragma unroll
      for (int i = 0; i < 4; ++i) {
        __builtin_amdgcn_global_load_lds(
            (const __attribute__((address_space(1))) void*)(pB + (size_t)i * 32 * K_TOT + kt * 64),
            (__attribute__((address_space(3))) void*)&lB[(tid + i * 256) * 8], 16, 0, 0);
      }
      __syncthreads();  // compiler drains vmcnt before barrier
#pragma unroll
      for (int kk = 0; kk < 2; ++kk) {
        const int e0 = kk * 32 + (lane >> 4) * 8;
        short8 a[4], b[4];
#pragma unroll
        for (int m = 0; m < 4; ++m) {
          const int r = wr * 64 + m * 16 + (lane & 15);
          a[m] = *reinterpret_cast<const short8*>(&lA[r * 64 + (e0 ^ ((r & 7) << 3))]);
        }
#pragma unroll
        for (int n = 0; n < 4; ++n) {
          const int r = wc * 64 + n * 16 + (lane & 15);
          b[n] = *reinterpret_cast<const short8*>(&lB[r * 64 + (e0 ^ ((r & 7) << 3))]);
        }
#pragma unroll
        for (int m = 0; m < 4; ++m)
#pragma unroll
          for (int n = 0; n < 4; ++n)
            acc[m][n] = __builtin_amdgcn_mfma_f32_16x16x32_bf16(a[m], b[n], acc[m][n], 0, 0, 0);
      }
    }
  }

  // ---- epilogue: scale by g[row][e0x+1], atomic accumulate (bias pre-initialized in out) ----
#pragma unroll
  for (int n = 0; n < 4; ++n) {
    const int cl = wc * 64 + n * 16 + (lane & 15);
#pragma unroll
    for (int m = 0; m < 4; ++m) {
#pragma unroll
      for (int reg = 0; reg < 4; ++reg) {
        const int r = wr * 64 + m * 16 + (lane >> 4) * 4 + reg;
        atomicAdd(&out[(size_t)(m0 + r) * P_DIM + n0 + cl], acc[m][n][reg] * gl[m * 4 + reg]);
      }
    }
  }
}

// ============================ FALLBACK PATH (round-2, passing) ============================

__global__ __launch_bounds__(256) void gate_kernel(const float* __restrict__ x,
                                                   const float* __restrict__ gw,
                                                   const float* __restrict__ gb,
                                                   float* __restrict__ gate) {
  const int row  = blockIdx.x * 4 + (threadIdx.x >> 6);
  const int lane = threadIdx.x & 63;
  const float* xr = x + (size_t)row * D_DIM;
  float acc[E_NUM];
#pragma unroll
  for (int e = 0; e < E_NUM; ++e) acc[e] = 0.f;
#pragma unroll
  for (int it = 0; it < 16; ++it) {
    const int d = it * 64 + lane;
    const float xv = xr[d];
    const float4* g4 = reinterpret_cast<const float4*>(gw + (size_t)d * E_NUM);
    float4 a = g4[0], b = g4[1];
    acc[0] += xv * a.x; acc[1] += xv * a.y; acc[2] += xv * a.z; acc[3] += xv * a.w;
    acc[4] += xv * b.x; acc[5] += xv * b.y; acc[6] += xv * b.z; acc[7] += xv * b.w;
  }
#pragma unroll
  for (int off = 32; off >= 1; off >>= 1) {
#pragma unroll
    for (int e = 0; e < E_NUM; ++e) acc[e] += __shfl_xor(acc[e], off, 64);
  }
  if (lane == 0) {
    float v[E_NUM], mx = -1e30f;
#pragma unroll
    for (int e = 0; e < E_NUM; ++e) { v[e] = acc[e] + gb[e]; mx = fmaxf(mx, v[e]); }
    float s = 0.f;
#pragma unroll
    for (int e = 0; e < E_NUM; ++e) { v[e] = expf(v[e] - mx); s += v[e]; }
    const float inv = 1.f / s;
#pragma unroll
    for (int e = 0; e < E_NUM; ++e) gate[(size_t)row * E_NUM + e] = v[e] * inv;
  }
}

__global__ __launch_bounds__(256) void wtrans_kernel(const float* __restrict__ w,
                                                     unsigned short* __restrict__ wt) {
  __shared__ float tile[64][65];
  const int e  = blockIdx.z;
  const int p0 = blockIdx.y * 64;
  const int d0 = blockIdx.x * 64;
  const int tx = threadIdx.x & 63;
  const int ty = threadIdx.x >> 6;
  const float* src = w + ((size_t)e * D_DIM + d0) * P_DIM + p0;
#pragma unroll
  for (int i = 0; i < 16; ++i) {
    const int dr = i * 4 + ty;
    tile[dr][tx] = src[(size_t)dr * P_DIM + tx];
  }
  __syncthreads();
  unsigned short* dst = wt + ((size_t)e * P_DIM + p0) * D_DIM + d0;
#pragma unroll
  for (int i = 0; i < 16; ++i) {
    const int pr = i * 4 + ty;
    const int cc = tx ^ ((pr & 7) << 3);
    dst[(size_t)pr * D_DIM + cc] = f2bf(tile[tx][pr]);
  }
}

__global__ __launch_bounds__(256, 2) void moe_gemm_kernel(
    const float* __restrict__ x,
    const unsigned short* __restrict__ wt,
    const float* __restrict__ gate,
    const float* __restrict__ eb,
    float* __restrict__ out) {
  __shared__ unsigned short lA[128 * 64];
  __shared__ unsigned short lB[128 * 64];
  __shared__ float lG[128 * 8];
  __shared__ float lBias[E_NUM * 128];

  const int tid  = threadIdx.x;
  const int lane = tid & 63;
  const int wid  = tid >> 6;
  const int wr   = wid >> 1, wc = wid & 1;
  const int m0   = blockIdx.x * 128;
  const int n0   = blockIdx.y * 128;

  reinterpret_cast<float4*>(lG)[tid] =
      reinterpret_cast<const float4*>(gate + (size_t)m0 * E_NUM)[tid];
  {
    const int e = tid >> 5, cc = (tid & 31) * 4;
    *reinterpret_cast<float4*>(&lBias[e * 128 + cc]) =
        *reinterpret_cast<const float4*>(&eb[(size_t)e * P_DIM + n0 + cc]);
  }
  __syncthreads();

  const int rA   = tid >> 1;
  const int colA = (tid & 1) * 32;
  const float* xrow = x + (size_t)(m0 + rA) * D_DIM + colA;

  f32x4 acc[4][4];
#pragma unroll
  for (int i = 0; i < 4; ++i)
#pragma unroll
    for (int jj = 0; jj < 4; ++jj)
#pragma unroll
      for (int k = 0; k < 4; ++k) acc[i][jj][k] = 0.f;

  for (int e = 0; e < E_NUM; ++e) {
    const float gs = lG[rA * 8 + e];
    const unsigned short* wte = wt + ((size_t)e * P_DIM + n0) * D_DIM;
    for (int kt = 0; kt < 16; ++kt) {
      __syncthreads();
      const float4* apv = reinterpret_cast<const float4*>(xrow + kt * 64);
#pragma unroll
      for (int jj = 0; jj < 4; ++jj) {
        float4 p = apv[2 * jj], q = apv[2 * jj + 1];
        u16x8 v;
        v[0] = f2bf(p.x * gs); v[1] = f2bf(p.y * gs);
        v[2] = f2bf(p.z * gs); v[3] = f2bf(p.w * gs);
        v[4] = f2bf(q.x * gs); v[5] = f2bf(q.y * gs);
        v[6] = f2bf(q.z * gs); v[7] = f2bf(q.w * gs);
        const int idx = rA * 64 + ((colA + jj * 8) ^ ((rA & 7) << 3));
        *reinterpret_cast<u16x8*>(&lA[idx]) = v;
      }
#pragma unroll
      for (int i = 0; i < 4; ++i) {
        const int u  = tid + i * 256;
        const int rr = u >> 3;
        const int cc = u & 7;
        const unsigned short* src = wte + (size_t)rr * D_DIM + kt * 64 + cc * 8;
        __builtin_amdgcn_global_load_lds(
            (const __attribute__((address_space(1))) void*)src,
            (__attribute__((address_space(3))) void*)&lB[u * 8], 16, 0, 0);
      }
      __syncthreads();
#pragma unroll
      for (int kk = 0; kk < 2; ++kk) {
        const int e0 = kk * 32 + (lane >> 4) * 8;
        short8 a[4], b[4];
#pragma unroll
        for (int m = 0; m < 4; ++m) {
          const int r = wr * 64 + m * 16 + (lane & 15);
          a[m] = *reinterpret_cast<const short8*>(&lA[r * 64 + (e0 ^ ((r & 7) << 3))]);
        }
#pragma unroll
        for (int n = 0; n < 4; ++n) {
          const int r = wc * 64 + n * 16 + (lane & 15);
          b[n] = *reinterpret_cast<const short8*>(&lB[r * 64 + (e0 ^ ((r & 7) << 3))]);
        }
#pragma unroll
        for (int m = 0; m < 4; ++m)
#pragma unroll
          for (int n = 0; n < 4; ++n)
            acc[m][n] = __builtin_amdgcn_mfma_f32_16x16x32_bf16(a[m], b[n], acc[m][n], 0, 0, 0);
      }
    }
  }

#pragma unroll
  for (int m = 0; m < 4; ++m) {
#pragma unroll
    for (int n = 0; n < 4; ++n) {
      const int rbase = wr * 64 + m * 16 + ((lane >> 4) * 4);
      const int cl    = wc * 64 + n * 16 + (lane & 15);
#pragma unroll
      for (int reg = 0; reg < 4; ++reg) {
        const int r = rbase + reg;
        float bsum = 0.f;
#pragma unroll
        for (int e = 0; e < E_NUM; ++e) bsum += lG[r * 8 + e] * lBias[e * 128 + cl];
        out[(size_t)(m0 + r) * P_DIM + n0 + cl] = acc[m][n][reg] + bsum;
      }
    }
  }
}

// ============================ launch ============================

extern "C" void kernel_launch(void* const* d_in, const int* in_sizes, int n_in,
                              void* d_out, int out_size, void* d_ws, size_t ws_size,
                              hipStream_t stream) {
  const float* x  = (const float*)d_in[0];
  const float* gw = (const float*)d_in[1];
  const float* gb = (const float*)d_in[2];
  const float* ew = (const float*)d_in[3];
  const float* eb = (const float*)d_in[4];
  float* out = (float*)d_out;

  char* ws = (char*)d_ws;
  float* gate        = (float*)ws;                     // 256 KiB
  unsigned short* wt = (unsigned short*)(ws + 262144); // 16 MiB

  const size_t need_new = 262144ull + 16777216ull + 16777216ull;  // gate + wt + xb

  if (ws_size >= need_new) {
    unsigned short* xbb = (unsigned short*)(ws + 262144 + 16777216);  // 16 MiB
    gate_xb_kernel<<<M_TOT / 4, 256, 0, stream>>>(x, gw, gb, gate, xbb);
    wtrans2_kernel<<<dim3(D_DIM / 64, P_DIM / 64, E_NUM), 256, 0, stream>>>(ew, wt);
    biasinit_kernel<<<M_TOT, 256, 0, stream>>>(gate, eb, out);
    gemm_sk4_kernel<<<2048, 256, 0, stream>>>(xbb, wt, gate, out);
  } else {
    gate_kernel<<<M_TOT / 4, 256, 0, stream>>>(x, gw, gb, gate);
    wtrans_kernel<<<dim3(D_DIM / 64, P_DIM / 64, E_NUM), 256, 0, stream>>>(ew, wt);
    moe_gemm_kernel<<<dim3(M_TOT / 128, P_DIM / 128), 256, 0, stream>>>(x, wt, gate, eb, out);
  }
}

// Round 12
// 236.170 us; speedup vs baseline: 1.1293x; 1.1293x over previous
//
#include <hip/hip_runtime.h>
#include <hip/hip_bf16.h>
#include <math.h>

#define M_TOT 8192
#define D_DIM 1024
#define E_NUM 8
#define P_DIM 1024
#define K_TOT (E_NUM * D_DIM)  // 8192

typedef __attribute__((ext_vector_type(8))) short short8;
typedef __attribute__((ext_vector_type(4))) float f32x4;
typedef __attribute__((ext_vector_type(8))) unsigned short u16x8;

// round-to-nearest-even f32 -> bf16 (finite inputs)
static __device__ __forceinline__ unsigned short f2bf(float f) {
  unsigned u = __builtin_bit_cast(unsigned, f);
  unsigned r = (u + 0x7fffu + ((u >> 16) & 1u)) >> 16;
  return (unsigned short)r;
}

// ---- fused gate+xb: softmax(x@gw+gb) -> gate[M,E]; xb[m][d]=bf16(x) swizzled per 64-short block ----
__global__ __launch_bounds__(256) void gate_xb_kernel(const float* __restrict__ x,
                                                      const float* __restrict__ gw,
                                                      const float* __restrict__ gb,
                                                      float* __restrict__ gate,
                                                      unsigned short* __restrict__ xb) {
  const int row  = blockIdx.x * 4 + (threadIdx.x >> 6);
  const int lane = threadIdx.x & 63;
  const float* xr = x + (size_t)row * D_DIM + lane * 16;
  float xx[16];
#pragma unroll
  for (int q = 0; q < 4; ++q) {
    const float4 v = reinterpret_cast<const float4*>(xr)[q];
    xx[q * 4 + 0] = v.x; xx[q * 4 + 1] = v.y; xx[q * 4 + 2] = v.z; xx[q * 4 + 3] = v.w;
  }
  float acc[E_NUM];
#pragma unroll
  for (int e = 0; e < E_NUM; ++e) acc[e] = 0.f;
#pragma unroll
  for (int j = 0; j < 16; ++j) {
    const int d = lane * 16 + j;
    const float4* g4 = reinterpret_cast<const float4*>(gw + (size_t)d * E_NUM);
    const float4 a = g4[0], b = g4[1];
    const float xv = xx[j];
    acc[0] += xv * a.x; acc[1] += xv * a.y; acc[2] += xv * a.z; acc[3] += xv * a.w;
    acc[4] += xv * b.x; acc[5] += xv * b.y; acc[6] += xv * b.z; acc[7] += xv * b.w;
  }
#pragma unroll
  for (int off = 32; off >= 1; off >>= 1) {
#pragma unroll
    for (int e = 0; e < E_NUM; ++e) acc[e] += __shfl_xor(acc[e], off, 64);
  }
  if (lane == 0) {
    float v[E_NUM], mx = -1e30f;
#pragma unroll
    for (int e = 0; e < E_NUM; ++e) { v[e] = acc[e] + gb[e]; mx = fmaxf(mx, v[e]); }
    float s = 0.f;
#pragma unroll
    for (int e = 0; e < E_NUM; ++e) { v[e] = expf(v[e] - mx); s += v[e]; }
    const float inv = 1.f / s;
#pragma unroll
    for (int e = 0; e < E_NUM; ++e) gate[(size_t)row * E_NUM + e] = v[e] * inv;
  }
  // xb: two swizzled 16B chunks per lane
  unsigned short* xrow = xb + (size_t)row * D_DIM;
#pragma unroll
  for (int h = 0; h < 2; ++h) {
    const int jd = lane * 2 + h;
    const int cbase = (jd >> 3) * 8 + ((jd & 7) ^ (row & 7));
    u16x8 v;
#pragma unroll
    for (int k = 0; k < 8; ++k) v[k] = f2bf(xx[h * 8 + k]);
    *reinterpret_cast<u16x8*>(&xrow[cbase * 8]) = v;
  }
}

// ---------------- W [E][D][P] f32 -> wt [P][E*D] bf16, swizzle baked per 64-short K-block ----------------
__global__ __launch_bounds__(256) void wtrans2_kernel(const float* __restrict__ w,
                                                      unsigned short* __restrict__ wt) {
  __shared__ float tile[64][65];
  const int e  = blockIdx.z;
  const int p0 = blockIdx.y * 64;
  const int d0 = blockIdx.x * 64;
  const int tx = threadIdx.x & 63;
  const int ty = threadIdx.x >> 6;
  const float* src = w + ((size_t)e * D_DIM + d0) * P_DIM + p0;
#pragma unroll
  for (int i = 0; i < 16; ++i) {
    const int dr = i * 4 + ty;
    tile[dr][tx] = src[(size_t)dr * P_DIM + tx];
  }
  __syncthreads();
#pragma unroll
  for (int i = 0; i < 16; ++i) {
    const int pr = i * 4 + ty;
    const int c = tx ^ ((pr & 7) << 3);  // involution, 16B-chunk granular
    wt[(size_t)(p0 + pr) * K_TOT + e * D_DIM + d0 + c] = f2bf(tile[tx][pr]);
  }
}

// ---------------- out[m][p] = sum_e gate[m,e]*eb[e,p]  (replaces memset; gemm atomically adds) ----------------
__global__ __launch_bounds__(256) void biasinit_kernel(const float* __restrict__ gate,
                                                       const float* __restrict__ eb,
                                                       float* __restrict__ out) {
  const int m = blockIdx.x;
  const int p = threadIdx.x * 4;
  const float* g = gate + (size_t)m * E_NUM;
  float4 s = {0.f, 0.f, 0.f, 0.f};
#pragma unroll
  for (int e = 0; e < E_NUM; ++e) {
    const float ge = g[e];
    const float4 b4 = *reinterpret_cast<const float4*>(&eb[(size_t)e * P_DIM + p]);
    s.x += ge * b4.x; s.y += ge * b4.y; s.z += ge * b4.z; s.w += ge * b4.w;
  }
  *reinterpret_cast<float4*>(&out[(size_t)m * P_DIM + p]) = s;
}

// ---- 8-wave Horner GEMM: 256x128 tile, BK=64, split-K=2 over expert halves, 48KB LDS, 2 blocks/CU ----
// Wave grid 4m x 2n, each wave 64x64 out. kh owns experts {4kh..4kh+3}, Horner rescale between them.
__global__ __launch_bounds__(512, 4) void gemm_b8_kernel(
    const unsigned short* __restrict__ xb,
    const unsigned short* __restrict__ wt,
    const float* __restrict__ gate,
    float* __restrict__ out) {
  __shared__ unsigned short lA[256 * 64];   // 32 KB
  __shared__ unsigned short lB[128 * 64];   // 16 KB  -> 48 KB total

  const int tid  = threadIdx.x;
  const int lane = tid & 63;
  const int wid  = tid >> 6;   // 0..7
  const int wm   = wid >> 1;   // 0..3
  const int wn   = wid & 1;    // 0..1
  const int l15  = lane & 15;

  // 512 blocks: XCD = bid&7 owns rectangle (8 mt x 4 nt x 2 kh) -> per-XCD HBM ~12MB.
  const int bid = blockIdx.x;
  const int xcd = bid & 7;
  const int idx = bid >> 3;        // 0..63
  const int kh  = idx & 1;
  const int ntl = (idx >> 1) & 3;
  const int mtl = idx >> 3;        // 0..7
  const int mt  = (xcd >> 1) * 8 + mtl;  // 0..31
  const int nt  = (xcd & 1) * 4 + ntl;   // 0..7
  const int m0  = mt * 256, n0 = nt * 128;

  f32x4 acc[4][4];
#pragma unroll
  for (int i = 0; i < 4; ++i)
#pragma unroll
    for (int j = 0; j < 4; ++j)
#pragma unroll
      for (int k = 0; k < 4; ++k) acc[i][j][k] = 0.f;

  const int c8  = tid & 7;   // 16B chunk within 64-short block
  const int rT  = tid >> 3;  // 0..63 staging base row
  const unsigned short* pA0 = xb + (size_t)(m0 + rT) * D_DIM + c8 * 8;
  const unsigned short* pB0 = wt + (size_t)(n0 + rT) * K_TOT + c8 * 8;

  float gl[16];  // final per-row gate scale g[row][4kh+3]

  for (int j = 0; j < 4; ++j) {
    const int eg = kh * 4 + j;
    if (j > 0) {
      // Horner rescale: acc *= g[row][eg-1] / g[row][eg]; cache g at last expert
#pragma unroll
      for (int m = 0; m < 4; ++m) {
#pragma unroll
        for (int reg = 0; reg < 4; ++reg) {
          const int r = wm * 64 + m * 16 + (lane >> 4) * 4 + reg;
          const float2 gp = *reinterpret_cast<const float2*>(&gate[(size_t)(m0 + r) * E_NUM + (eg - 1)]);
          if (j == 3) gl[m * 4 + reg] = gp.y;
          const float ratio = gp.x / gp.y;
#pragma unroll
          for (int n = 0; n < 4; ++n) acc[m][n][reg] *= ratio;
        }
      }
    }
    const unsigned short* pB = pB0 + (size_t)eg * D_DIM;
    for (int kt = 0; kt < 16; ++kt) {
      __syncthreads();  // previous tile's LDS reads complete
#pragma unroll
      for (int i = 0; i < 4; ++i) {  // A: 256 rows, 4 chunks/thread
        __builtin_amdgcn_global_load_lds(
            (const __attribute__((address_space(1))) void*)(pA0 + (size_t)(i * 64) * D_DIM + kt * 64),
            (__attribute__((address_space(3))) void*)&lA[(tid + i * 512) * 8], 16, 0, 0);
      }
#pragma unroll
      for (int i = 0; i < 2; ++i) {  // B: 128 rows, 2 chunks/thread
        __builtin_amdgcn_global_load_lds(
            (const __attribute__((address_space(1))) void*)(pB + (size_t)(i * 64) * K_TOT + kt * 64),
            (__attribute__((address_space(3))) void*)&lB[(tid + i * 512) * 8], 16, 0, 0);
      }
      __syncthreads();  // compiler drains vmcnt before barrier
#pragma unroll
      for (int kk = 0; kk < 2; ++kk) {
        const int e0 = kk * 32 + (lane >> 4) * 8;
        short8 a[4], b[4];
#pragma unroll
        for (int m = 0; m < 4; ++m) {
          const int r = wm * 64 + m * 16 + l15;
          a[m] = *reinterpret_cast<const short8*>(&lA[r * 64 + (e0 ^ ((r & 7) << 3))]);
        }
#pragma unroll
        for (int n = 0; n < 4; ++n) {
          const int r = wn * 64 + n * 16 + l15;
          b[n] = *reinterpret_cast<const short8*>(&lB[r * 64 + (e0 ^ ((r & 7) << 3))]);
        }
#pragma unroll
        for (int m = 0; m < 4; ++m)
#pragma unroll
          for (int n = 0; n < 4; ++n)
            acc[m][n] = __builtin_amdgcn_mfma_f32_16x16x32_bf16(a[m], b[n], acc[m][n], 0, 0, 0);
      }
    }
  }

  // ---- epilogue: scale by g[row][4kh+3], atomic accumulate (bias pre-initialized in out) ----
#pragma unroll
  for (int n = 0; n < 4; ++n) {
    const int cl = wn * 64 + n * 16 + l15;
#pragma unroll
    for (int m = 0; m < 4; ++m) {
#pragma unroll
      for (int reg = 0; reg < 4; ++reg) {
        const int r = wm * 64 + m * 16 + (lane >> 4) * 4 + reg;
        atomicAdd(&out[(size_t)(m0 + r) * P_DIM + n0 + cl], acc[m][n][reg] * gl[m * 4 + reg]);
      }
    }
  }
}

// ============================ FALLBACK PATH (round-2, passing) ============================

__global__ __launch_bounds__(256) void gate_kernel(const float* __restrict__ x,
                                                   const float* __restrict__ gw,
                                                   const float* __restrict__ gb,
                                                   float* __restrict__ gate) {
  const int row  = blockIdx.x * 4 + (threadIdx.x >> 6);
  const int lane = threadIdx.x & 63;
  const float* xr = x + (size_t)row * D_DIM;
  float acc[E_NUM];
#pragma unroll
  for (int e = 0; e < E_NUM; ++e) acc[e] = 0.f;
#pragma unroll
  for (int it = 0; it < 16; ++it) {
    const int d = it * 64 + lane;
    const float xv = xr[d];
    const float4* g4 = reinterpret_cast<const float4*>(gw + (size_t)d * E_NUM);
    float4 a = g4[0], b = g4[1];
    acc[0] += xv * a.x; acc[1] += xv * a.y; acc[2] += xv * a.z; acc[3] += xv * a.w;
    acc[4] += xv * b.x; acc[5] += xv * b.y; acc[6] += xv * b.z; acc[7] += xv * b.w;
  }
#pragma unroll
  for (int off = 32; off >= 1; off >>= 1) {
#pragma unroll
    for (int e = 0; e < E_NUM; ++e) acc[e] += __shfl_xor(acc[e], off, 64);
  }
  if (lane == 0) {
    float v[E_NUM], mx = -1e30f;
#pragma unroll
    for (int e = 0; e < E_NUM; ++e) { v[e] = acc[e] + gb[e]; mx = fmaxf(mx, v[e]); }
    float s = 0.f;
#pragma unroll
    for (int e = 0; e < E_NUM; ++e) { v[e] = expf(v[e] - mx); s += v[e]; }
    const float inv = 1.f / s;
#pragma unroll
    for (int e = 0; e < E_NUM; ++e) gate[(size_t)row * E_NUM + e] = v[e] * inv;
  }
}

__global__ __launch_bounds__(256) void wtrans_kernel(const float* __restrict__ w,
                                                     unsigned short* __restrict__ wt) {
  __shared__ float tile[64][65];
  const int e  = blockIdx.z;
  const int p0 = blockIdx.y * 64;
  const int d0 = blockIdx.x * 64;
  const int tx = threadIdx.x & 63;
  const int ty = threadIdx.x >> 6;
  const float* src = w + ((size_t)e * D_DIM + d0) * P_DIM + p0;
#pragma unroll
  for (int i = 0; i < 16; ++i) {
    const int dr = i * 4 + ty;
    tile[dr][tx] = src[(size_t)dr * P_DIM + tx];
  }
  __syncthreads();
  unsigned short* dst = wt + ((size_t)e * P_DIM + p0) * D_DIM + d0;
#pragma unroll
  for (int i = 0; i < 16; ++i) {
    const int pr = i * 4 + ty;
    const int cc = tx ^ ((pr & 7) << 3);
    dst[(size_t)pr * D_DIM + cc] = f2bf(tile[tx][pr]);
  }
}

__global__ __launch_bounds__(256, 2) void moe_gemm_kernel(
    const float* __restrict__ x,
    const unsigned short* __restrict__ wt,
    const float* __restrict__ gate,
    const float* __restrict__ eb,
    float* __restrict__ out) {
  __shared__ unsigned short lA[128 * 64];
  __shared__ unsigned short lB[128 * 64];
  __shared__ float lG[128 * 8];
  __shared__ float lBias[E_NUM * 128];

  const int tid  = threadIdx.x;
  const int lane = tid & 63;
  const int wid  = tid >> 6;
  const int wr   = wid >> 1, wc = wid & 1;
  const int m0   = blockIdx.x * 128;
  const int n0   = blockIdx.y * 128;

  reinterpret_cast<float4*>(lG)[tid] =
      reinterpret_cast<const float4*>(gate + (size_t)m0 * E_NUM)[tid];
  {
    const int e = tid >> 5, cc = (tid & 31) * 4;
    *reinterpret_cast<float4*>(&lBias[e * 128 + cc]) =
        *reinterpret_cast<const float4*>(&eb[(size_t)e * P_DIM + n0 + cc]);
  }
  __syncthreads();

  const int rA   = tid >> 1;
  const int colA = (tid & 1) * 32;
  const float* xrow = x + (size_t)(m0 + rA) * D_DIM + colA;

  f32x4 acc[4][4];
#pragma unroll
  for (int i = 0; i < 4; ++i)
#pragma unroll
    for (int jj = 0; jj < 4; ++jj)
#pragma unroll
      for (int k = 0; k < 4; ++k) acc[i][jj][k] = 0.f;

  for (int e = 0; e < E_NUM; ++e) {
    const float gs = lG[rA * 8 + e];
    const unsigned short* wte = wt + ((size_t)e * P_DIM + n0) * D_DIM;
    for (int kt = 0; kt < 16; ++kt) {
      __syncthreads();
      const float4* apv = reinterpret_cast<const float4*>(xrow + kt * 64);
#pragma unroll
      for (int jj = 0; jj < 4; ++jj) {
        float4 p = apv[2 * jj], q = apv[2 * jj + 1];
        u16x8 v;
        v[0] = f2bf(p.x * gs); v[1] = f2bf(p.y * gs);
        v[2] = f2bf(p.z * gs); v[3] = f2bf(p.w * gs);
        v[4] = f2bf(q.x * gs); v[5] = f2bf(q.y * gs);
        v[6] = f2bf(q.z * gs); v[7] = f2bf(q.w * gs);
        const int idx = rA * 64 + ((colA + jj * 8) ^ ((rA & 7) << 3));
        *reinterpret_cast<u16x8*>(&lA[idx]) = v;
      }
#pragma unroll
      for (int i = 0; i < 4; ++i) {
        const int u  = tid + i * 256;
        const int rr = u >> 3;
        const int cc = u & 7;
        const unsigned short* src = wte + (size_t)rr * D_DIM + kt * 64 + cc * 8;
        __builtin_amdgcn_global_load_lds(
            (const __attribute__((address_space(1))) void*)src,
            (__attribute__((address_space(3))) void*)&lB[u * 8], 16, 0, 0);
      }
      __syncthreads();
#pragma unroll
      for (int kk = 0; kk < 2; ++kk) {
        const int e0 = kk * 32 + (lane >> 4) * 8;
        short8 a[4], b[4];
#pragma unroll
        for (int m = 0; m < 4; ++m) {
          const int r = wr * 64 + m * 16 + (lane & 15);
          a[m] = *reinterpret_cast<const short8*>(&lA[r * 64 + (e0 ^ ((r & 7) << 3))]);
        }
#pragma unroll
        for (int n = 0; n < 4; ++n) {
          const int r = wc * 64 + n * 16 + (lane & 15);
          b[n] = *reinterpret_cast<const short8*>(&lB[r * 64 + (e0 ^ ((r & 7) << 3))]);
        }
#pragma unroll
        for (int m = 0; m < 4; ++m)
#pragma unroll
          for (int n = 0; n < 4; ++n)
            acc[m][n] = __builtin_amdgcn_mfma_f32_16x16x32_bf16(a[m], b[n], acc[m][n], 0, 0, 0);
      }
    }
  }

#pragma unroll
  for (int m = 0; m < 4; ++m) {
#pragma unroll
    for (int n = 0; n < 4; ++n) {
      const int rbase = wr * 64 + m * 16 + ((lane >> 4) * 4);
      const int cl    = wc * 64 + n * 16 + (lane & 15);
#pragma unroll
      for (int reg = 0; reg < 4; ++reg) {
        const int r = rbase + reg;
        float bsum = 0.f;
#pragma unroll
        for (int e = 0; e < E_NUM; ++e) bsum += lG[r * 8 + e] * lBias[e * 128 + cl];
        out[(size_t)(m0 + r) * P_DIM + n0 + cl] = acc[m][n][reg] + bsum;
      }
    }
  }
}

// ============================ launch ============================

extern "C" void kernel_launch(void* const* d_in, const int* in_sizes, int n_in,
                              void* d_out, int out_size, void* d_ws, size_t ws_size,
                              hipStream_t stream) {
  const float* x  = (const float*)d_in[0];
  const float* gw = (const float*)d_in[1];
  const float* gb = (const float*)d_in[2];
  const float* ew = (const float*)d_in[3];
  const float* eb = (const float*)d_in[4];
  float* out = (float*)d_out;

  char* ws = (char*)d_ws;
  float* gate        = (float*)ws;                     // 256 KiB
  unsigned short* wt = (unsigned short*)(ws + 262144); // 16 MiB

  const size_t need_new = 262144ull + 16777216ull + 16777216ull;  // gate + wt + xb

  if (ws_size >= need_new) {
    unsigned short* xbb = (unsigned short*)(ws + 262144 + 16777216);  // 16 MiB
    gate_xb_kernel<<<M_TOT / 4, 256, 0, stream>>>(x, gw, gb, gate, xbb);
    wtrans2_kernel<<<dim3(D_DIM / 64, P_DIM / 64, E_NUM), 256, 0, stream>>>(ew, wt);
    biasinit_kernel<<<M_TOT, 256, 0, stream>>>(gate, eb, out);
    gemm_b8_kernel<<<512, 512, 0, stream>>>(xbb, wt, gate, out);
  } else {
    gate_kernel<<<M_TOT / 4, 256, 0, stream>>>(x, gw, gb, gate);
    wtrans_kernel<<<dim3(D_DIM / 64, P_DIM / 64, E_NUM), 256, 0, stream>>>(ew, wt);
    moe_gemm_kernel<<<dim3(M_TOT / 128, P_DIM / 128), 256, 0, stream>>>(x, wt, gate, eb, out);
  }
}

// Round 13
// 215.419 us; speedup vs baseline: 1.2381x; 1.0963x over previous
//
#include <hip/hip_runtime.h>
#include <hip/hip_bf16.h>
#include <math.h>

#define M_TOT 8192
#define D_DIM 1024
#define E_NUM 8
#define P_DIM 1024
#define K_TOT (E_NUM * D_DIM)  // 8192

typedef __attribute__((ext_vector_type(8))) short short8;
typedef __attribute__((ext_vector_type(4))) float f32x4;
typedef __attribute__((ext_vector_type(8))) unsigned short u16x8;

// round-to-nearest-even f32 -> bf16 (finite inputs)
static __device__ __forceinline__ unsigned short f2bf(float f) {
  unsigned u = __builtin_bit_cast(unsigned, f);
  unsigned r = (u + 0x7fffu + ((u >> 16) & 1u)) >> 16;
  return (unsigned short)r;
}

// ---- fused gate+xb: softmax(x@gw+gb) -> gate[M,E]; xb[m][d]=bf16(x) swizzled per 64-short block ----
__global__ __launch_bounds__(256) void gate_xb_kernel(const float* __restrict__ x,
                                                      const float* __restrict__ gw,
                                                      const float* __restrict__ gb,
                                                      float* __restrict__ gate,
                                                      unsigned short* __restrict__ xb) {
  const int row  = blockIdx.x * 4 + (threadIdx.x >> 6);
  const int lane = threadIdx.x & 63;
  const float* xr = x + (size_t)row * D_DIM + lane * 16;
  float xx[16];
#pragma unroll
  for (int q = 0; q < 4; ++q) {
    const float4 v = reinterpret_cast<const float4*>(xr)[q];
    xx[q * 4 + 0] = v.x; xx[q * 4 + 1] = v.y; xx[q * 4 + 2] = v.z; xx[q * 4 + 3] = v.w;
  }
  float acc[E_NUM];
#pragma unroll
  for (int e = 0; e < E_NUM; ++e) acc[e] = 0.f;
#pragma unroll
  for (int j = 0; j < 16; ++j) {
    const int d = lane * 16 + j;
    const float4* g4 = reinterpret_cast<const float4*>(gw + (size_t)d * E_NUM);
    const float4 a = g4[0], b = g4[1];
    const float xv = xx[j];
    acc[0] += xv * a.x; acc[1] += xv * a.y; acc[2] += xv * a.z; acc[3] += xv * a.w;
    acc[4] += xv * b.x; acc[5] += xv * b.y; acc[6] += xv * b.z; acc[7] += xv * b.w;
  }
#pragma unroll
  for (int off = 32; off >= 1; off >>= 1) {
#pragma unroll
    for (int e = 0; e < E_NUM; ++e) acc[e] += __shfl_xor(acc[e], off, 64);
  }
  if (lane == 0) {
    float v[E_NUM], mx = -1e30f;
#pragma unroll
    for (int e = 0; e < E_NUM; ++e) { v[e] = acc[e] + gb[e]; mx = fmaxf(mx, v[e]); }
    float s = 0.f;
#pragma unroll
    for (int e = 0; e < E_NUM; ++e) { v[e] = expf(v[e] - mx); s += v[e]; }
    const float inv = 1.f / s;
#pragma unroll
    for (int e = 0; e < E_NUM; ++e) gate[(size_t)row * E_NUM + e] = v[e] * inv;
  }
  // xb: two swizzled 16B chunks per lane
  unsigned short* xrow = xb + (size_t)row * D_DIM;
#pragma unroll
  for (int h = 0; h < 2; ++h) {
    const int jd = lane * 2 + h;
    const int cbase = (jd >> 3) * 8 + ((jd & 7) ^ (row & 7));
    u16x8 v;
#pragma unroll
    for (int k = 0; k < 8; ++k) v[k] = f2bf(xx[h * 8 + k]);
    *reinterpret_cast<u16x8*>(&xrow[cbase * 8]) = v;
  }
}

// ---------------- W [E][D][P] f32 -> wt [P][E*D] bf16, swizzle baked per 64-short K-block ----------------
__global__ __launch_bounds__(256) void wtrans2_kernel(const float* __restrict__ w,
                                                      unsigned short* __restrict__ wt) {
  __shared__ float tile[64][65];
  const int e  = blockIdx.z;
  const int p0 = blockIdx.y * 64;
  const int d0 = blockIdx.x * 64;
  const int tx = threadIdx.x & 63;
  const int ty = threadIdx.x >> 6;
  const float* src = w + ((size_t)e * D_DIM + d0) * P_DIM + p0;
#pragma unroll
  for (int i = 0; i < 16; ++i) {
    const int dr = i * 4 + ty;
    tile[dr][tx] = src[(size_t)dr * P_DIM + tx];
  }
  __syncthreads();
#pragma unroll
  for (int i = 0; i < 16; ++i) {
    const int pr = i * 4 + ty;
    const int c = tx ^ ((pr & 7) << 3);  // involution, 16B-chunk granular
    wt[(size_t)(p0 + pr) * K_TOT + e * D_DIM + d0 + c] = f2bf(tile[tx][pr]);
  }
}

// ---------------- out[m][p] = sum_e gate[m,e]*eb[e,p]  (replaces memset; gemm atomically adds) ----------------
__global__ __launch_bounds__(256) void biasinit_kernel(const float* __restrict__ gate,
                                                       const float* __restrict__ eb,
                                                       float* __restrict__ out) {
  const int m = blockIdx.x;
  const int p = threadIdx.x * 4;
  const float* g = gate + (size_t)m * E_NUM;
  float4 s = {0.f, 0.f, 0.f, 0.f};
#pragma unroll
  for (int e = 0; e < E_NUM; ++e) {
    const float ge = g[e];
    const float4 b4 = *reinterpret_cast<const float4*>(&eb[(size_t)e * P_DIM + p]);
    s.x += ge * b4.x; s.y += ge * b4.y; s.z += ge * b4.z; s.w += ge * b4.w;
  }
  *reinterpret_cast<float4*>(&out[(size_t)m * P_DIM + p]) = s;
}

// ---- Horner-gated expert-loop GEMM (round-10 structure, bias-free epilogue):
// 128x128 tile, BK=64, 4 waves, split-K=2 over expert halves, 36KB LDS.
__global__ __launch_bounds__(256, 4) void gemm_ex2_kernel(
    const unsigned short* __restrict__ xb,
    const unsigned short* __restrict__ wt,
    const float* __restrict__ gate,
    float* __restrict__ out) {
  __shared__ unsigned short lA[128 * 64];   // 16 KB
  __shared__ unsigned short lB[128 * 64];   // 16 KB
  __shared__ float lG[128 * 8];             // 4 KB  -> 36 KB total

  const int tid  = threadIdx.x;
  const int lane = tid & 63;
  const int wid  = tid >> 6;
  const int wr   = wid >> 1, wc = wid & 1;

  // 1024 blocks: xcd = bid&7 = nt (2MB wt slice L2-resident); idx: kh = idx&1, mt = idx>>1.
  const int bid = blockIdx.x;
  const int nt  = bid & 7;
  const int idx = bid >> 3;
  const int kh  = idx & 1;
  const int mt  = idx >> 1;
  const int m0  = mt * 128, n0 = nt * 128;

  reinterpret_cast<float4*>(lG)[tid] =
      reinterpret_cast<const float4*>(gate + (size_t)m0 * E_NUM)[tid];

  f32x4 acc[4][4];
#pragma unroll
  for (int i = 0; i < 4; ++i)
#pragma unroll
    for (int j = 0; j < 4; ++j)
#pragma unroll
      for (int k = 0; k < 4; ++k) acc[i][j][k] = 0.f;

  const int r0 = tid >> 3;  // 0..31
  const int c8 = tid & 7;   // 16B chunk within 64-short block
  const unsigned short* pAb = xb + (size_t)(m0 + r0) * D_DIM + c8 * 8;
  const unsigned short* pBb = wt + (size_t)(n0 + r0) * K_TOT + c8 * 8;

  for (int e = 0; e < 4; ++e) {
    const int eg = kh * 4 + e;
    if (e > 0) {
      // Horner rescale: acc *= g[row][eg-1] / g[row][eg]  (softmax gates bounded below, safe)
#pragma unroll
      for (int m = 0; m < 4; ++m) {
#pragma unroll
        for (int reg = 0; reg < 4; ++reg) {
          const int r = wr * 64 + m * 16 + (lane >> 4) * 4 + reg;
          const float ratio = lG[r * 8 + (eg - 1)] / lG[r * 8 + eg];
#pragma unroll
          for (int n = 0; n < 4; ++n) acc[m][n][reg] *= ratio;
        }
      }
    }
    const unsigned short* pB = pBb + (size_t)eg * D_DIM;
    for (int kt = 0; kt < 16; ++kt) {
      __syncthreads();  // previous tile's LDS reads complete
#pragma unroll
      for (int i = 0; i < 4; ++i) {
        __builtin_amdgcn_global_load_lds(
            (const __attribute__((address_space(1))) void*)(pAb + (size_t)i * 32 * D_DIM + kt * 64),
            (__attribute__((address_space(3))) void*)&lA[(tid + i * 256) * 8], 16, 0, 0);
      }
#pragma unroll
      for (int i = 0; i < 4; ++i) {
        __builtin_amdgcn_global_load_lds(
            (const __attribute__((address_space(1))) void*)(pB + (size_t)i * 32 * K_TOT + kt * 64),
            (__attribute__((address_space(3))) void*)&lB[(tid + i * 256) * 8], 16, 0, 0);
      }
      __syncthreads();  // compiler drains vmcnt before barrier
#pragma unroll
      for (int kk = 0; kk < 2; ++kk) {
        const int e0 = kk * 32 + (lane >> 4) * 8;
        short8 a[4], b[4];
#pragma unroll
        for (int m = 0; m < 4; ++m) {
          const int r = wr * 64 + m * 16 + (lane & 15);
          a[m] = *reinterpret_cast<const short8*>(&lA[r * 64 + (e0 ^ ((r & 7) << 3))]);
        }
#pragma unroll
        for (int n = 0; n < 4; ++n) {
          const int r = wc * 64 + n * 16 + (lane & 15);
          b[n] = *reinterpret_cast<const short8*>(&lB[r * 64 + (e0 ^ ((r & 7) << 3))]);
        }
#pragma unroll
        for (int m = 0; m < 4; ++m)
#pragma unroll
          for (int n = 0; n < 4; ++n)
            acc[m][n] = __builtin_amdgcn_mfma_f32_16x16x32_bf16(a[m], b[n], acc[m][n], 0, 0, 0);
      }
    }
  }

  // ---- epilogue: final Horner scale by g[row][kh*4+3]; atomic accumulate (bias pre-initialized) ----
#pragma unroll
  for (int n = 0; n < 4; ++n) {
    const int cl = wc * 64 + n * 16 + (lane & 15);
#pragma unroll
    for (int m = 0; m < 4; ++m) {
#pragma unroll
      for (int reg = 0; reg < 4; ++reg) {
        const int r  = wr * 64 + m * 16 + (lane >> 4) * 4 + reg;
        const float gl = lG[r * 8 + kh * 4 + 3];
        atomicAdd(&out[(size_t)(m0 + r) * P_DIM + n0 + cl], acc[m][n][reg] * gl);
      }
    }
  }
}

// ============================ FALLBACK PATH (round-2, passing) ============================

__global__ __launch_bounds__(256) void gate_kernel(const float* __restrict__ x,
                                                   const float* __restrict__ gw,
                                                   const float* __restrict__ gb,
                                                   float* __restrict__ gate) {
  const int row  = blockIdx.x * 4 + (threadIdx.x >> 6);
  const int lane = threadIdx.x & 63;
  const float* xr = x + (size_t)row * D_DIM;
  float acc[E_NUM];
#pragma unroll
  for (int e = 0; e < E_NUM; ++e) acc[e] = 0.f;
#pragma unroll
  for (int it = 0; it < 16; ++it) {
    const int d = it * 64 + lane;
    const float xv = xr[d];
    const float4* g4 = reinterpret_cast<const float4*>(gw + (size_t)d * E_NUM);
    float4 a = g4[0], b = g4[1];
    acc[0] += xv * a.x; acc[1] += xv * a.y; acc[2] += xv * a.z; acc[3] += xv * a.w;
    acc[4] += xv * b.x; acc[5] += xv * b.y; acc[6] += xv * b.z; acc[7] += xv * b.w;
  }
#pragma unroll
  for (int off = 32; off >= 1; off >>= 1) {
#pragma unroll
    for (int e = 0; e < E_NUM; ++e) acc[e] += __shfl_xor(acc[e], off, 64);
  }
  if (lane == 0) {
    float v[E_NUM], mx = -1e30f;
#pragma unroll
    for (int e = 0; e < E_NUM; ++e) { v[e] = acc[e] + gb[e]; mx = fmaxf(mx, v[e]); }
    float s = 0.f;
#pragma unroll
    for (int e = 0; e < E_NUM; ++e) { v[e] = expf(v[e] - mx); s += v[e]; }
    const float inv = 1.f / s;
#pragma unroll
    for (int e = 0; e < E_NUM; ++e) gate[(size_t)row * E_NUM + e] = v[e] * inv;
  }
}

__global__ __launch_bounds__(256) void wtrans_kernel(const float* __restrict__ w,
                                                     unsigned short* __restrict__ wt) {
  __shared__ float tile[64][65];
  const int e  = blockIdx.z;
  const int p0 = blockIdx.y * 64;
  const int d0 = blockIdx.x * 64;
  const int tx = threadIdx.x & 63;
  const int ty = threadIdx.x >> 6;
  const float* src = w + ((size_t)e * D_DIM + d0) * P_DIM + p0;
#pragma unroll
  for (int i = 0; i < 16; ++i) {
    const int dr = i * 4 + ty;
    tile[dr][tx] = src[(size_t)dr * P_DIM + tx];
  }
  __syncthreads();
  unsigned short* dst = wt + ((size_t)e * P_DIM + p0) * D_DIM + d0;
#pragma unroll
  for (int i = 0; i < 16; ++i) {
    const int pr = i * 4 + ty;
    const int cc = tx ^ ((pr & 7) << 3);
    dst[(size_t)pr * D_DIM + cc] = f2bf(tile[tx][pr]);
  }
}

__global__ __launch_bounds__(256, 2) void moe_gemm_kernel(
    const float* __restrict__ x,
    const unsigned short* __restrict__ wt,
    const float* __restrict__ gate,
    const float* __restrict__ eb,
    float* __restrict__ out) {
  __shared__ unsigned short lA[128 * 64];
  __shared__ unsigned short lB[128 * 64];
  __shared__ float lG[128 * 8];
  __shared__ float lBias[E_NUM * 128];

  const int tid  = threadIdx.x;
  const int lane = tid & 63;
  const int wid  = tid >> 6;
  const int wr   = wid >> 1, wc = wid & 1;
  const int m0   = blockIdx.x * 128;
  const int n0   = blockIdx.y * 128;

  reinterpret_cast<float4*>(lG)[tid] =
      reinterpret_cast<const float4*>(gate + (size_t)m0 * E_NUM)[tid];
  {
    const int e = tid >> 5, cc = (tid & 31) * 4;
    *reinterpret_cast<float4*>(&lBias[e * 128 + cc]) =
        *reinterpret_cast<const float4*>(&eb[(size_t)e * P_DIM + n0 + cc]);
  }
  __syncthreads();

  const int rA   = tid >> 1;
  const int colA = (tid & 1) * 32;
  const float* xrow = x + (size_t)(m0 + rA) * D_DIM + colA;

  f32x4 acc[4][4];
#pragma unroll
  for (int i = 0; i < 4; ++i)
#pragma unroll
    for (int jj = 0; jj < 4; ++jj)
#pragma unroll
      for (int k = 0; k < 4; ++k) acc[i][jj][k] = 0.f;

  for (int e = 0; e < E_NUM; ++e) {
    const float gs = lG[rA * 8 + e];
    const unsigned short* wte = wt + ((size_t)e * P_DIM + n0) * D_DIM;
    for (int kt = 0; kt < 16; ++kt) {
      __syncthreads();
      const float4* apv = reinterpret_cast<const float4*>(xrow + kt * 64);
#pragma unroll
      for (int jj = 0; jj < 4; ++jj) {
        float4 p = apv[2 * jj], q = apv[2 * jj + 1];
        u16x8 v;
        v[0] = f2bf(p.x * gs); v[1] = f2bf(p.y * gs);
        v[2] = f2bf(p.z * gs); v[3] = f2bf(p.w * gs);
        v[4] = f2bf(q.x * gs); v[5] = f2bf(q.y * gs);
        v[6] = f2bf(q.z * gs); v[7] = f2bf(q.w * gs);
        const int idx = rA * 64 + ((colA + jj * 8) ^ ((rA & 7) << 3));
        *reinterpret_cast<u16x8*>(&lA[idx]) = v;
      }
#pragma unroll
      for (int i = 0; i < 4; ++i) {
        const int u  = tid + i * 256;
        const int rr = u >> 3;
        const int cc = u & 7;
        const unsigned short* src = wte + (size_t)rr * D_DIM + kt * 64 + cc * 8;
        __builtin_amdgcn_global_load_lds(
            (const __attribute__((address_space(1))) void*)src,
            (__attribute__((address_space(3))) void*)&lB[u * 8], 16, 0, 0);
      }
      __syncthreads();
#pragma unroll
      for (int kk = 0; kk < 2; ++kk) {
        const int e0 = kk * 32 + (lane >> 4) * 8;
        short8 a[4], b[4];
#pragma unroll
        for (int m = 0; m < 4; ++m) {
          const int r = wr * 64 + m * 16 + (lane & 15);
          a[m] = *reinterpret_cast<const short8*>(&lA[r * 64 + (e0 ^ ((r & 7) << 3))]);
        }
#pragma unroll
        for (int n = 0; n < 4; ++n) {
          const int r = wc * 64 + n * 16 + (lane & 15);
          b[n] = *reinterpret_cast<const short8*>(&lB[r * 64 + (e0 ^ ((r & 7) << 3))]);
        }
#pragma unroll
        for (int m = 0; m < 4; ++m)
#pragma unroll
          for (int n = 0; n < 4; ++n)
            acc[m][n] = __builtin_amdgcn_mfma_f32_16x16x32_bf16(a[m], b[n], acc[m][n], 0, 0, 0);
      }
    }
  }

#pragma unroll
  for (int m = 0; m < 4; ++m) {
#pragma unroll
    for (int n = 0; n < 4; ++n) {
      const int rbase = wr * 64 + m * 16 + ((lane >> 4) * 4);
      const int cl    = wc * 64 + n * 16 + (lane & 15);
#pragma unroll
      for (int reg = 0; reg < 4; ++reg) {
        const int r = rbase + reg;
        float bsum = 0.f;
#pragma unroll
        for (int e = 0; e < E_NUM; ++e) bsum += lG[r * 8 + e] * lBias[e * 128 + cl];
        out[(size_t)(m0 + r) * P_DIM + n0 + cl] = acc[m][n][reg] + bsum;
      }
    }
  }
}

// ============================ launch ============================

extern "C" void kernel_launch(void* const* d_in, const int* in_sizes, int n_in,
                              void* d_out, int out_size, void* d_ws, size_t ws_size,
                              hipStream_t stream) {
  const float* x  = (const float*)d_in[0];
  const float* gw = (const float*)d_in[1];
  const float* gb = (const float*)d_in[2];
  const float* ew = (const float*)d_in[3];
  const float* eb = (const float*)d_in[4];
  float* out = (float*)d_out;

  char* ws = (char*)d_ws;
  float* gate        = (float*)ws;                     // 256 KiB
  unsigned short* wt = (unsigned short*)(ws + 262144); // 16 MiB

  const size_t need_new = 262144ull + 16777216ull + 16777216ull;  // gate + wt + xb

  if (ws_size >= need_new) {
    unsigned short* xbb = (unsigned short*)(ws + 262144 + 16777216);  // 16 MiB
    gate_xb_kernel<<<M_TOT / 4, 256, 0, stream>>>(x, gw, gb, gate, xbb);
    wtrans2_kernel<<<dim3(D_DIM / 64, P_DIM / 64, E_NUM), 256, 0, stream>>>(ew, wt);
    biasinit_kernel<<<M_TOT, 256, 0, stream>>>(gate, eb, out);
    gemm_ex2_kernel<<<1024, 256, 0, stream>>>(xbb, wt, gate, out);
  } else {
    gate_kernel<<<M_TOT / 4, 256, 0, stream>>>(x, gw, gb, gate);
    wtrans_kernel<<<dim3(D_DIM / 64, P_DIM / 64, E_NUM), 256, 0, stream>>>(ew, wt);
    moe_gemm_kernel<<<dim3(M_TOT / 128, P_DIM / 128), 256, 0, stream>>>(x, wt, gate, eb, out);
  }
}

// Round 14
// 200.693 us; speedup vs baseline: 1.3290x; 1.0734x over previous
//
#include <hip/hip_runtime.h>
#include <hip/hip_bf16.h>
#include <math.h>

#define M_TOT 8192
#define D_DIM 1024
#define E_NUM 8
#define P_DIM 1024
#define K_TOT (E_NUM * D_DIM)  // 8192

typedef __attribute__((ext_vector_type(8))) short short8;
typedef __attribute__((ext_vector_type(4))) float f32x4;
typedef __attribute__((ext_vector_type(8))) unsigned short u16x8;

// round-to-nearest-even f32 -> bf16 (finite inputs)
static __device__ __forceinline__ unsigned short f2bf(float f) {
  unsigned u = __builtin_bit_cast(unsigned, f);
  unsigned r = (u + 0x7fffu + ((u >> 16) & 1u)) >> 16;
  return (unsigned short)r;
}

// ---------------- gate: softmax(x @ gate_w + gate_b) -> [M, E] fp32 (coalesced, round-10 form) ----------------
__global__ __launch_bounds__(256) void gate_kernel(const float* __restrict__ x,
                                                   const float* __restrict__ gw,
                                                   const float* __restrict__ gb,
                                                   float* __restrict__ gate) {
  const int row  = blockIdx.x * 4 + (threadIdx.x >> 6);
  const int lane = threadIdx.x & 63;
  const float* xr = x + (size_t)row * D_DIM;
  float acc[E_NUM];
#pragma unroll
  for (int e = 0; e < E_NUM; ++e) acc[e] = 0.f;
#pragma unroll
  for (int it = 0; it < 16; ++it) {
    const int d = it * 64 + lane;
    const float xv = xr[d];
    const float4* g4 = reinterpret_cast<const float4*>(gw + (size_t)d * E_NUM);
    float4 a = g4[0], b = g4[1];
    acc[0] += xv * a.x; acc[1] += xv * a.y; acc[2] += xv * a.z; acc[3] += xv * a.w;
    acc[4] += xv * b.x; acc[5] += xv * b.y; acc[6] += xv * b.z; acc[7] += xv * b.w;
  }
#pragma unroll
  for (int off = 32; off >= 1; off >>= 1) {
#pragma unroll
    for (int e = 0; e < E_NUM; ++e) acc[e] += __shfl_xor(acc[e], off, 64);
  }
  if (lane == 0) {
    float v[E_NUM], mx = -1e30f;
#pragma unroll
    for (int e = 0; e < E_NUM; ++e) { v[e] = acc[e] + gb[e]; mx = fmaxf(mx, v[e]); }
    float s = 0.f;
#pragma unroll
    for (int e = 0; e < E_NUM; ++e) { v[e] = expf(v[e] - mx); s += v[e]; }
    const float inv = 1.f / s;
#pragma unroll
    for (int e = 0; e < E_NUM; ++e) gate[(size_t)row * E_NUM + e] = v[e] * inv;
  }
}

// ---------------- W [E][D][P] f32 -> wt [P][E*D] bf16, swizzle baked per 64-short K-block ----------------
__global__ __launch_bounds__(256) void wtrans2_kernel(const float* __restrict__ w,
                                                      unsigned short* __restrict__ wt) {
  __shared__ float tile[64][65];
  const int e  = blockIdx.z;
  const int p0 = blockIdx.y * 64;
  const int d0 = blockIdx.x * 64;
  const int tx = threadIdx.x & 63;
  const int ty = threadIdx.x >> 6;
  const float* src = w + ((size_t)e * D_DIM + d0) * P_DIM + p0;
#pragma unroll
  for (int i = 0; i < 16; ++i) {
    const int dr = i * 4 + ty;
    tile[dr][tx] = src[(size_t)dr * P_DIM + tx];
  }
  __syncthreads();
#pragma unroll
  for (int i = 0; i < 16; ++i) {
    const int pr = i * 4 + ty;
    const int c = tx ^ ((pr & 7) << 3);  // involution, 16B-chunk granular
    wt[(size_t)(p0 + pr) * K_TOT + e * D_DIM + d0 + c] = f2bf(tile[tx][pr]);
  }
}

// ---------------- xb[m][d] = bf16(x[m][d]), swizzle baked per 64-short K-block (round-10 form) ----------------
__global__ __launch_bounds__(256) void xb_kernel(const float* __restrict__ x,
                                                 unsigned short* __restrict__ xb) {
  const int tid = threadIdx.x;
  const int m   = blockIdx.x * 2 + (tid >> 7);
  const int jd  = tid & 127;
  const float4* xp = reinterpret_cast<const float4*>(x + (size_t)m * D_DIM + jd * 8);
  const float4 p = xp[0], q = xp[1];
  const int cbase = (jd >> 3) * 8 + ((jd & 7) ^ (m & 7));
  u16x8 v;
  v[0] = f2bf(p.x); v[1] = f2bf(p.y); v[2] = f2bf(p.z); v[3] = f2bf(p.w);
  v[4] = f2bf(q.x); v[5] = f2bf(q.y); v[6] = f2bf(q.z); v[7] = f2bf(q.w);
  *reinterpret_cast<u16x8*>(&xb[(size_t)m * D_DIM + cbase * 8]) = v;
}

// ---------------- out[m][p] = sum_e gate[m,e]*eb[e,p]  (replaces memset; gemm atomically adds) ----------------
__global__ __launch_bounds__(256) void biasinit_kernel(const float* __restrict__ gate,
                                                       const float* __restrict__ eb,
                                                       float* __restrict__ out) {
  const int m = blockIdx.x;
  const int p = threadIdx.x * 4;
  const float* g = gate + (size_t)m * E_NUM;
  float4 s = {0.f, 0.f, 0.f, 0.f};
#pragma unroll
  for (int e = 0; e < E_NUM; ++e) {
    const float ge = g[e];
    const float4 b4 = *reinterpret_cast<const float4*>(&eb[(size_t)e * P_DIM + p]);
    s.x += ge * b4.x; s.y += ge * b4.y; s.z += ge * b4.z; s.w += ge * b4.w;
  }
  *reinterpret_cast<float4*>(&out[(size_t)m * P_DIM + p]) = s;
}

// ---- Horner-gated expert-loop GEMM (round-10 structure, bias-free epilogue):
// 128x128 tile, BK=64, 4 waves, split-K=2 over expert halves, 36KB LDS.
__global__ __launch_bounds__(256, 4) void gemm_ex2_kernel(
    const unsigned short* __restrict__ xb,
    const unsigned short* __restrict__ wt,
    const float* __restrict__ gate,
    float* __restrict__ out) {
  __shared__ unsigned short lA[128 * 64];   // 16 KB
  __shared__ unsigned short lB[128 * 64];   // 16 KB
  __shared__ float lG[128 * 8];             // 4 KB  -> 36 KB total

  const int tid  = threadIdx.x;
  const int lane = tid & 63;
  const int wid  = tid >> 6;
  const int wr   = wid >> 1, wc = wid & 1;

  // 1024 blocks: xcd = bid&7 = nt (2MB wt slice L2-resident); idx: kh = idx&1, mt = idx>>1.
  const int bid = blockIdx.x;
  const int nt  = bid & 7;
  const int idx = bid >> 3;
  const int kh  = idx & 1;
  const int mt  = idx >> 1;
  const int m0  = mt * 128, n0 = nt * 128;

  reinterpret_cast<float4*>(lG)[tid] =
      reinterpret_cast<const float4*>(gate + (size_t)m0 * E_NUM)[tid];

  f32x4 acc[4][4];
#pragma unroll
  for (int i = 0; i < 4; ++i)
#pragma unroll
    for (int j = 0; j < 4; ++j)
#pragma unroll
      for (int k = 0; k < 4; ++k) acc[i][j][k] = 0.f;

  const int r0 = tid >> 3;  // 0..31
  const int c8 = tid & 7;   // 16B chunk within 64-short block
  const unsigned short* pAb = xb + (size_t)(m0 + r0) * D_DIM + c8 * 8;
  const unsigned short* pBb = wt + (size_t)(n0 + r0) * K_TOT + c8 * 8;

  for (int e = 0; e < 4; ++e) {
    const int eg = kh * 4 + e;
    if (e > 0) {
      // Horner rescale: acc *= g[row][eg-1] / g[row][eg]  (softmax gates bounded below, safe)
#pragma unroll
      for (int m = 0; m < 4; ++m) {
#pragma unroll
        for (int reg = 0; reg < 4; ++reg) {
          const int r = wr * 64 + m * 16 + (lane >> 4) * 4 + reg;
          const float ratio = lG[r * 8 + (eg - 1)] / lG[r * 8 + eg];
#pragma unroll
          for (int n = 0; n < 4; ++n) acc[m][n][reg] *= ratio;
        }
      }
    }
    const unsigned short* pB = pBb + (size_t)eg * D_DIM;
    for (int kt = 0; kt < 16; ++kt) {
      __syncthreads();  // previous tile's LDS reads complete
#pragma unroll
      for (int i = 0; i < 4; ++i) {
        __builtin_amdgcn_global_load_lds(
            (const __attribute__((address_space(1))) void*)(pAb + (size_t)i * 32 * D_DIM + kt * 64),
            (__attribute__((address_space(3))) void*)&lA[(tid + i * 256) * 8], 16, 0, 0);
      }
#pragma unroll
      for (int i = 0; i < 4; ++i) {
        __builtin_amdgcn_global_load_lds(
            (const __attribute__((address_space(1))) void*)(pB + (size_t)i * 32 * K_TOT + kt * 64),
            (__attribute__((address_space(3))) void*)&lB[(tid + i * 256) * 8], 16, 0, 0);
      }
      __syncthreads();  // compiler drains vmcnt before barrier
#pragma unroll
      for (int kk = 0; kk < 2; ++kk) {
        const int e0 = kk * 32 + (lane >> 4) * 8;
        short8 a[4], b[4];
#pragma unroll
        for (int m = 0; m < 4; ++m) {
          const int r = wr * 64 + m * 16 + (lane & 15);
          a[m] = *reinterpret_cast<const short8*>(&lA[r * 64 + (e0 ^ ((r & 7) << 3))]);
        }
#pragma unroll
        for (int n = 0; n < 4; ++n) {
          const int r = wc * 64 + n * 16 + (lane & 15);
          b[n] = *reinterpret_cast<const short8*>(&lB[r * 64 + (e0 ^ ((r & 7) << 3))]);
        }
#pragma unroll
        for (int m = 0; m < 4; ++m)
#pragma unroll
          for (int n = 0; n < 4; ++n)
            acc[m][n] = __builtin_amdgcn_mfma_f32_16x16x32_bf16(a[m], b[n], acc[m][n], 0, 0, 0);
      }
    }
  }

  // ---- epilogue: final Horner scale by g[row][kh*4+3]; atomic accumulate (bias pre-initialized) ----
#pragma unroll
  for (int n = 0; n < 4; ++n) {
    const int cl = wc * 64 + n * 16 + (lane & 15);
#pragma unroll
    for (int m = 0; m < 4; ++m) {
#pragma unroll
      for (int reg = 0; reg < 4; ++reg) {
        const int r  = wr * 64 + m * 16 + (lane >> 4) * 4 + reg;
        const float gl = lG[r * 8 + kh * 4 + 3];
        atomicAdd(&out[(size_t)(m0 + r) * P_DIM + n0 + cl], acc[m][n][reg] * gl);
      }
    }
  }
}

// ============================ FALLBACK PATH (round-2, passing) ============================

__global__ __launch_bounds__(256) void wtrans_kernel(const float* __restrict__ w,
                                                     unsigned short* __restrict__ wt) {
  __shared__ float tile[64][65];
  const int e  = blockIdx.z;
  const int p0 = blockIdx.y * 64;
  const int d0 = blockIdx.x * 64;
  const int tx = threadIdx.x & 63;
  const int ty = threadIdx.x >> 6;
  const float* src = w + ((size_t)e * D_DIM + d0) * P_DIM + p0;
#pragma unroll
  for (int i = 0; i < 16; ++i) {
    const int dr = i * 4 + ty;
    tile[dr][tx] = src[(size_t)dr * P_DIM + tx];
  }
  __syncthreads();
  unsigned short* dst = wt + ((size_t)e * P_DIM + p0) * D_DIM + d0;
#pragma unroll
  for (int i = 0; i < 16; ++i) {
    const int pr = i * 4 + ty;
    const int cc = tx ^ ((pr & 7) << 3);
    dst[(size_t)pr * D_DIM + cc] = f2bf(tile[tx][pr]);
  }
}

__global__ __launch_bounds__(256, 2) void moe_gemm_kernel(
    const float* __restrict__ x,
    const unsigned short* __restrict__ wt,
    const float* __restrict__ gate,
    const float* __restrict__ eb,
    float* __restrict__ out) {
  __shared__ unsigned short lA[128 * 64];
  __shared__ unsigned short lB[128 * 64];
  __shared__ float lG[128 * 8];
  __shared__ float lBias[E_NUM * 128];

  const int tid  = threadIdx.x;
  const int lane = tid & 63;
  const int wid  = tid >> 6;
  const int wr   = wid >> 1, wc = wid & 1;
  const int m0   = blockIdx.x * 128;
  const int n0   = blockIdx.y * 128;

  reinterpret_cast<float4*>(lG)[tid] =
      reinterpret_cast<const float4*>(gate + (size_t)m0 * E_NUM)[tid];
  {
    const int e = tid >> 5, cc = (tid & 31) * 4;
    *reinterpret_cast<float4*>(&lBias[e * 128 + cc]) =
        *reinterpret_cast<const float4*>(&eb[(size_t)e * P_DIM + n0 + cc]);
  }
  __syncthreads();

  const int rA   = tid >> 1;
  const int colA = (tid & 1) * 32;
  const float* xrow = x + (size_t)(m0 + rA) * D_DIM + colA;

  f32x4 acc[4][4];
#pragma unroll
  for (int i = 0; i < 4; ++i)
#pragma unroll
    for (int jj = 0; jj < 4; ++jj)
#pragma unroll
      for (int k = 0; k < 4; ++k) acc[i][jj][k] = 0.f;

  for (int e = 0; e < E_NUM; ++e) {
    const float gs = lG[rA * 8 + e];
    const unsigned short* wte = wt + ((size_t)e * P_DIM + n0) * D_DIM;
    for (int kt = 0; kt < 16; ++kt) {
      __syncthreads();
      const float4* apv = reinterpret_cast<const float4*>(xrow + kt * 64);
#pragma unroll
      for (int jj = 0; jj < 4; ++jj) {
        float4 p = apv[2 * jj], q = apv[2 * jj + 1];
        u16x8 v;
        v[0] = f2bf(p.x * gs); v[1] = f2bf(p.y * gs);
        v[2] = f2bf(p.z * gs); v[3] = f2bf(p.w * gs);
        v[4] = f2bf(q.x * gs); v[5] = f2bf(q.y * gs);
        v[6] = f2bf(q.z * gs); v[7] = f2bf(q.w * gs);
        const int idxw = rA * 64 + ((colA + jj * 8) ^ ((rA & 7) << 3));
        *reinterpret_cast<u16x8*>(&lA[idxw]) = v;
      }
#pragma unroll
      for (int i = 0; i < 4; ++i) {
        const int u  = tid + i * 256;
        const int rr = u >> 3;
        const int cc = u & 7;
        const unsigned short* src = wte + (size_t)rr * D_DIM + kt * 64 + cc * 8;
        __builtin_amdgcn_global_load_lds(
            (const __attribute__((address_space(1))) void*)src,
            (__attribute__((address_space(3))) void*)&lB[u * 8], 16, 0, 0);
      }
      __syncthreads();
#pragma unroll
      for (int kk = 0; kk < 2; ++kk) {
        const int e0 = kk * 32 + (lane >> 4) * 8;
        short8 a[4], b[4];
#pragma unroll
        for (int m = 0; m < 4; ++m) {
          const int r = wr * 64 + m * 16 + (lane & 15);
          a[m] = *reinterpret_cast<const short8*>(&lA[r * 64 + (e0 ^ ((r & 7) << 3))]);
        }
#pragma unroll
        for (int n = 0; n < 4; ++n) {
          const int r = wc * 64 + n * 16 + (lane & 15);
          b[n] = *reinterpret_cast<const short8*>(&lB[r * 64 + (e0 ^ ((r & 7) << 3))]);
        }
#pragma unroll
        for (int m = 0; m < 4; ++m)
#pragma unroll
          for (int n = 0; n < 4; ++n)
            acc[m][n] = __builtin_amdgcn_mfma_f32_16x16x32_bf16(a[m], b[n], acc[m][n], 0, 0, 0);
      }
    }
  }

#pragma unroll
  for (int m = 0; m < 4; ++m) {
#pragma unroll
    for (int n = 0; n < 4; ++n) {
      const int rbase = wr * 64 + m * 16 + ((lane >> 4) * 4);
      const int cl    = wc * 64 + n * 16 + (lane & 15);
#pragma unroll
      for (int reg = 0; reg < 4; ++reg) {
        const int r = rbase + reg;
        float bsum = 0.f;
#pragma unroll
        for (int e = 0; e < E_NUM; ++e) bsum += lG[r * 8 + e] * lBias[e * 128 + cl];
        out[(size_t)(m0 + r) * P_DIM + n0 + cl] = acc[m][n][reg] + bsum;
      }
    }
  }
}

// ============================ launch ============================

extern "C" void kernel_launch(void* const* d_in, const int* in_sizes, int n_in,
                              void* d_out, int out_size, void* d_ws, size_t ws_size,
                              hipStream_t stream) {
  const float* x  = (const float*)d_in[0];
  const float* gw = (const float*)d_in[1];
  const float* gb = (const float*)d_in[2];
  const float* ew = (const float*)d_in[3];
  const float* eb = (const float*)d_in[4];
  float* out = (float*)d_out;

  char* ws = (char*)d_ws;
  float* gate        = (float*)ws;                     // 256 KiB
  unsigned short* wt = (unsigned short*)(ws + 262144); // 16 MiB

  const size_t need_new = 262144ull + 16777216ull + 16777216ull;  // gate + wt + xb

  gate_kernel<<<M_TOT / 4, 256, 0, stream>>>(x, gw, gb, gate);

  if (ws_size >= need_new) {
    unsigned short* xbb = (unsigned short*)(ws + 262144 + 16777216);  // 16 MiB
    wtrans2_kernel<<<dim3(D_DIM / 64, P_DIM / 64, E_NUM), 256, 0, stream>>>(ew, wt);
    xb_kernel<<<M_TOT / 2, 256, 0, stream>>>(x, xbb);
    biasinit_kernel<<<M_TOT, 256, 0, stream>>>(gate, eb, out);
    gemm_ex2_kernel<<<1024, 256, 0, stream>>>(xbb, wt, gate, out);
  } else {
    wtrans_kernel<<<dim3(D_DIM / 64, P_DIM / 64, E_NUM), 256, 0, stream>>>(ew, wt);
    moe_gemm_kernel<<<dim3(M_TOT / 128, P_DIM / 128), 256, 0, stream>>>(x, wt, gate, eb, out);
  }
}

// Round 15
// 193.288 us; speedup vs baseline: 1.3799x; 1.0383x over previous
//
#include <hip/hip_runtime.h>
#include <hip/hip_bf16.h>
#include <math.h>

#define M_TOT 8192
#define D_DIM 1024
#define E_NUM 8
#define P_DIM 1024
#define K_TOT (E_NUM * D_DIM)  // 8192

typedef __attribute__((ext_vector_type(8))) short short8;
typedef __attribute__((ext_vector_type(4))) float f32x4;
typedef __attribute__((ext_vector_type(8))) unsigned short u16x8;

// round-to-nearest-even f32 -> bf16 (finite inputs)
static __device__ __forceinline__ unsigned short f2bf(float f) {
  unsigned u = __builtin_bit_cast(unsigned, f);
  unsigned r = (u + 0x7fffu + ((u >> 16) & 1u)) >> 16;
  return (unsigned short)r;
}

// ---- fused prep: per row -> gate softmax + xb (bf16, swizzled) + out bias-init ----
// Wave = one row. Gate loop stays coalesced (d = it*64+lane); bf16 goes through LDS so the
// xb vector stores read contiguous bytes; butterfly leaves sums in ALL lanes so each lane
// does softmax redundantly and writes its coalesced float4 slice of the bias-init row.
__global__ __launch_bounds__(256) void prep_m_kernel(const float* __restrict__ x,
                                                     const float* __restrict__ gw,
                                                     const float* __restrict__ gb,
                                                     const float* __restrict__ eb,
                                                     float* __restrict__ gate,
                                                     unsigned short* __restrict__ xb,
                                                     float* __restrict__ out) {
  __shared__ __align__(16) unsigned short lx[4][1024];  // 8 KB
  const int wv   = threadIdx.x >> 6;
  const int lane = threadIdx.x & 63;
  const int row  = blockIdx.x * 4 + wv;
  const float* xr = x + (size_t)row * D_DIM;

  float acc[E_NUM];
#pragma unroll
  for (int e = 0; e < E_NUM; ++e) acc[e] = 0.f;
#pragma unroll
  for (int it = 0; it < 16; ++it) {
    const int d = it * 64 + lane;
    const float xv = xr[d];
    lx[wv][d] = f2bf(xv);
    const float4* g4 = reinterpret_cast<const float4*>(gw + (size_t)d * E_NUM);
    const float4 a = g4[0], b = g4[1];
    acc[0] += xv * a.x; acc[1] += xv * a.y; acc[2] += xv * a.z; acc[3] += xv * a.w;
    acc[4] += xv * b.x; acc[5] += xv * b.y; acc[6] += xv * b.z; acc[7] += xv * b.w;
  }
#pragma unroll
  for (int off = 32; off >= 1; off >>= 1) {
#pragma unroll
    for (int e = 0; e < E_NUM; ++e) acc[e] += __shfl_xor(acc[e], off, 64);
  }
  __syncthreads();  // publish LDS bf16 row

  // softmax (all lanes hold full sums after butterfly)
  float g[E_NUM], mx = -1e30f;
#pragma unroll
  for (int e = 0; e < E_NUM; ++e) { g[e] = acc[e] + gb[e]; mx = fmaxf(mx, g[e]); }
  float s = 0.f;
#pragma unroll
  for (int e = 0; e < E_NUM; ++e) { g[e] = expf(g[e] - mx); s += g[e]; }
  const float inv = 1.f / s;
#pragma unroll
  for (int e = 0; e < E_NUM; ++e) g[e] *= inv;
  if (lane == 0) {
#pragma unroll
    for (int e = 0; e < E_NUM; ++e) gate[(size_t)row * E_NUM + e] = g[e];
  }

  // xb: two swizzled 16B chunks per lane, sourced from LDS (contiguous)
  unsigned short* xrow = xb + (size_t)row * D_DIM;
#pragma unroll
  for (int h = 0; h < 2; ++h) {
    const int jd = lane * 2 + h;
    const int cbase = (jd >> 3) * 8 + ((jd & 7) ^ (row & 7));
    const u16x8 vv = *reinterpret_cast<const u16x8*>(&lx[wv][jd * 8]);
    *reinterpret_cast<u16x8*>(&xrow[cbase * 8]) = vv;
  }

  // bias-init: out[row][p] = sum_e g[e]*eb[e][p], coalesced float4 per lane
  float* orow = out + (size_t)row * P_DIM;
#pragma unroll
  for (int q = 0; q < 4; ++q) {
    const int p = q * 256 + lane * 4;
    float4 sv = {0.f, 0.f, 0.f, 0.f};
#pragma unroll
    for (int e = 0; e < E_NUM; ++e) {
      const float4 b4 = *reinterpret_cast<const float4*>(&eb[(size_t)e * P_DIM + p]);
      sv.x += g[e] * b4.x; sv.y += g[e] * b4.y; sv.z += g[e] * b4.z; sv.w += g[e] * b4.w;
    }
    *reinterpret_cast<float4*>(&orow[p]) = sv;
  }
}

// ---------------- W [E][D][P] f32 -> wt [P][E*D] bf16, swizzle baked per 64-short K-block ----------------
__global__ __launch_bounds__(256) void wtrans2_kernel(const float* __restrict__ w,
                                                      unsigned short* __restrict__ wt) {
  __shared__ float tile[64][65];
  const int e  = blockIdx.z;
  const int p0 = blockIdx.y * 64;
  const int d0 = blockIdx.x * 64;
  const int tx = threadIdx.x & 63;
  const int ty = threadIdx.x >> 6;
  const float* src = w + ((size_t)e * D_DIM + d0) * P_DIM + p0;
#pragma unroll
  for (int i = 0; i < 16; ++i) {
    const int dr = i * 4 + ty;
    tile[dr][tx] = src[(size_t)dr * P_DIM + tx];
  }
  __syncthreads();
#pragma unroll
  for (int i = 0; i < 16; ++i) {
    const int pr = i * 4 + ty;
    const int c = tx ^ ((pr & 7) << 3);  // involution, 16B-chunk granular
    wt[(size_t)(p0 + pr) * K_TOT + e * D_DIM + d0 + c] = f2bf(tile[tx][pr]);
  }
}

// ---- Horner-gated expert-loop GEMM (round-10 structure, bias-free epilogue):
// 128x128 tile, BK=64, 4 waves, split-K=2 over expert halves, 36KB LDS.
__global__ __launch_bounds__(256, 4) void gemm_ex2_kernel(
    const unsigned short* __restrict__ xb,
    const unsigned short* __restrict__ wt,
    const float* __restrict__ gate,
    float* __restrict__ out) {
  __shared__ unsigned short lA[128 * 64];   // 16 KB
  __shared__ unsigned short lB[128 * 64];   // 16 KB
  __shared__ float lG[128 * 8];             // 4 KB  -> 36 KB total

  const int tid  = threadIdx.x;
  const int lane = tid & 63;
  const int wid  = tid >> 6;
  const int wr   = wid >> 1, wc = wid & 1;

  // 1024 blocks: xcd = bid&7 = nt (2MB wt slice L2-resident); idx: kh = idx&1, mt = idx>>1.
  const int bid = blockIdx.x;
  const int nt  = bid & 7;
  const int idx = bid >> 3;
  const int kh  = idx & 1;
  const int mt  = idx >> 1;
  const int m0  = mt * 128, n0 = nt * 128;

  reinterpret_cast<float4*>(lG)[tid] =
      reinterpret_cast<const float4*>(gate + (size_t)m0 * E_NUM)[tid];

  f32x4 acc[4][4];
#pragma unroll
  for (int i = 0; i < 4; ++i)
#pragma unroll
    for (int j = 0; j < 4; ++j)
#pragma unroll
      for (int k = 0; k < 4; ++k) acc[i][j][k] = 0.f;

  const int r0 = tid >> 3;  // 0..31
  const int c8 = tid & 7;   // 16B chunk within 64-short block
  const unsigned short* pAb = xb + (size_t)(m0 + r0) * D_DIM + c8 * 8;
  const unsigned short* pBb = wt + (size_t)(n0 + r0) * K_TOT + c8 * 8;

  for (int e = 0; e < 4; ++e) {
    const int eg = kh * 4 + e;
    if (e > 0) {
      // Horner rescale: acc *= g[row][eg-1] / g[row][eg]  (softmax gates bounded below, safe)
#pragma unroll
      for (int m = 0; m < 4; ++m) {
#pragma unroll
        for (int reg = 0; reg < 4; ++reg) {
          const int r = wr * 64 + m * 16 + (lane >> 4) * 4 + reg;
          const float ratio = lG[r * 8 + (eg - 1)] / lG[r * 8 + eg];
#pragma unroll
          for (int n = 0; n < 4; ++n) acc[m][n][reg] *= ratio;
        }
      }
    }
    const unsigned short* pB = pBb + (size_t)eg * D_DIM;
    for (int kt = 0; kt < 16; ++kt) {
      __syncthreads();  // previous tile's LDS reads complete
#pragma unroll
      for (int i = 0; i < 4; ++i) {
        __builtin_amdgcn_global_load_lds(
            (const __attribute__((address_space(1))) void*)(pAb + (size_t)i * 32 * D_DIM + kt * 64),
            (__attribute__((address_space(3))) void*)&lA[(tid + i * 256) * 8], 16, 0, 0);
      }
#pragma unroll
      for (int i = 0; i < 4; ++i) {
        __builtin_amdgcn_global_load_lds(
            (const __attribute__((address_space(1))) void*)(pB + (size_t)i * 32 * K_TOT + kt * 64),
            (__attribute__((address_space(3))) void*)&lB[(tid + i * 256) * 8], 16, 0, 0);
      }
      __syncthreads();  // compiler drains vmcnt before barrier
#pragma unroll
      for (int kk = 0; kk < 2; ++kk) {
        const int e0 = kk * 32 + (lane >> 4) * 8;
        short8 a[4], b[4];
#pragma unroll
        for (int m = 0; m < 4; ++m) {
          const int r = wr * 64 + m * 16 + (lane & 15);
          a[m] = *reinterpret_cast<const short8*>(&lA[r * 64 + (e0 ^ ((r & 7) << 3))]);
        }
#pragma unroll
        for (int n = 0; n < 4; ++n) {
          const int r = wc * 64 + n * 16 + (lane & 15);
          b[n] = *reinterpret_cast<const short8*>(&lB[r * 64 + (e0 ^ ((r & 7) << 3))]);
        }
#pragma unroll
        for (int m = 0; m < 4; ++m)
#pragma unroll
          for (int n = 0; n < 4; ++n)
            acc[m][n] = __builtin_amdgcn_mfma_f32_16x16x32_bf16(a[m], b[n], acc[m][n], 0, 0, 0);
      }
    }
  }

  // ---- epilogue: final Horner scale by g[row][kh*4+3]; atomic accumulate (bias pre-initialized) ----
#pragma unroll
  for (int n = 0; n < 4; ++n) {
    const int cl = wc * 64 + n * 16 + (lane & 15);
#pragma unroll
    for (int m = 0; m < 4; ++m) {
#pragma unroll
      for (int reg = 0; reg < 4; ++reg) {
        const int r  = wr * 64 + m * 16 + (lane >> 4) * 4 + reg;
        const float gl = lG[r * 8 + kh * 4 + 3];
        atomicAdd(&out[(size_t)(m0 + r) * P_DIM + n0 + cl], acc[m][n][reg] * gl);
      }
    }
  }
}

// ============================ FALLBACK PATH (round-2, passing) ============================

__global__ __launch_bounds__(256) void gate_kernel(const float* __restrict__ x,
                                                   const float* __restrict__ gw,
                                                   const float* __restrict__ gb,
                                                   float* __restrict__ gate) {
  const int row  = blockIdx.x * 4 + (threadIdx.x >> 6);
  const int lane = threadIdx.x & 63;
  const float* xr = x + (size_t)row * D_DIM;
  float acc[E_NUM];
#pragma unroll
  for (int e = 0; e < E_NUM; ++e) acc[e] = 0.f;
#pragma unroll
  for (int it = 0; it < 16; ++it) {
    const int d = it * 64 + lane;
    const float xv = xr[d];
    const float4* g4 = reinterpret_cast<const float4*>(gw + (size_t)d * E_NUM);
    float4 a = g4[0], b = g4[1];
    acc[0] += xv * a.x; acc[1] += xv * a.y; acc[2] += xv * a.z; acc[3] += xv * a.w;
    acc[4] += xv * b.x; acc[5] += xv * b.y; acc[6] += xv * b.z; acc[7] += xv * b.w;
  }
#pragma unroll
  for (int off = 32; off >= 1; off >>= 1) {
#pragma unroll
    for (int e = 0; e < E_NUM; ++e) acc[e] += __shfl_xor(acc[e], off, 64);
  }
  if (lane == 0) {
    float v[E_NUM], mx = -1e30f;
#pragma unroll
    for (int e = 0; e < E_NUM; ++e) { v[e] = acc[e] + gb[e]; mx = fmaxf(mx, v[e]); }
    float s = 0.f;
#pragma unroll
    for (int e = 0; e < E_NUM; ++e) { v[e] = expf(v[e] - mx); s += v[e]; }
    const float inv = 1.f / s;
#pragma unroll
    for (int e = 0; e < E_NUM; ++e) gate[(size_t)row * E_NUM + e] = v[e] * inv;
  }
}

__global__ __launch_bounds__(256) void wtrans_kernel(const float* __restrict__ w,
                                                     unsigned short* __restrict__ wt) {
  __shared__ float tile[64][65];
  const int e  = blockIdx.z;
  const int p0 = blockIdx.y * 64;
  const int d0 = blockIdx.x * 64;
  const int tx = threadIdx.x & 63;
  const int ty = threadIdx.x >> 6;
  const float* src = w + ((size_t)e * D_DIM + d0) * P_DIM + p0;
#pragma unroll
  for (int i = 0; i < 16; ++i) {
    const int dr = i * 4 + ty;
    tile[dr][tx] = src[(size_t)dr * P_DIM + tx];
  }
  __syncthreads();
  unsigned short* dst = wt + ((size_t)e * P_DIM + p0) * D_DIM + d0;
#pragma unroll
  for (int i = 0; i < 16; ++i) {
    const int pr = i * 4 + ty;
    const int cc = tx ^ ((pr & 7) << 3);
    dst[(size_t)pr * D_DIM + cc] = f2bf(tile[tx][pr]);
  }
}

__global__ __launch_bounds__(256, 2) void moe_gemm_kernel(
    const float* __restrict__ x,
    const unsigned short* __restrict__ wt,
    const float* __restrict__ gate,
    const float* __restrict__ eb,
    float* __restrict__ out) {
  __shared__ unsigned short lA[128 * 64];
  __shared__ unsigned short lB[128 * 64];
  __shared__ float lG[128 * 8];
  __shared__ float lBias[E_NUM * 128];

  const int tid  = threadIdx.x;
  const int lane = tid & 63;
  const int wid  = tid >> 6;
  const int wr   = wid >> 1, wc = wid & 1;
  const int m0   = blockIdx.x * 128;
  const int n0   = blockIdx.y * 128;

  reinterpret_cast<float4*>(lG)[tid] =
      reinterpret_cast<const float4*>(gate + (size_t)m0 * E_NUM)[tid];
  {
    const int e = tid >> 5, cc = (tid & 31) * 4;
    *reinterpret_cast<float4*>(&lBias[e * 128 + cc]) =
        *reinterpret_cast<const float4*>(&eb[(size_t)e * P_DIM + n0 + cc]);
  }
  __syncthreads();

  const int rA   = tid >> 1;
  const int colA = (tid & 1) * 32;
  const float* xrow = x + (size_t)(m0 + rA) * D_DIM + colA;

  f32x4 acc[4][4];
#pragma unroll
  for (int i = 0; i < 4; ++i)
#pragma unroll
    for (int jj = 0; jj < 4; ++jj)
#pragma unroll
      for (int k = 0; k < 4; ++k) acc[i][jj][k] = 0.f;

  for (int e = 0; e < E_NUM; ++e) {
    const float gs = lG[rA * 8 + e];
    const unsigned short* wte = wt + ((size_t)e * P_DIM + n0) * D_DIM;
    for (int kt = 0; kt < 16; ++kt) {
      __syncthreads();
      const float4* apv = reinterpret_cast<const float4*>(xrow + kt * 64);
#pragma unroll
      for (int jj = 0; jj < 4; ++jj) {
        float4 p = apv[2 * jj], q = apv[2 * jj + 1];
        u16x8 v;
        v[0] = f2bf(p.x * gs); v[1] = f2bf(p.y * gs);
        v[2] = f2bf(p.z * gs); v[3] = f2bf(p.w * gs);
        v[4] = f2bf(q.x * gs); v[5] = f2bf(q.y * gs);
        v[6] = f2bf(q.z * gs); v[7] = f2bf(q.w * gs);
        const int idxw = rA * 64 + ((colA + jj * 8) ^ ((rA & 7) << 3));
        *reinterpret_cast<u16x8*>(&lA[idxw]) = v;
      }
#pragma unroll
      for (int i = 0; i < 4; ++i) {
        const int u  = tid + i * 256;
        const int rr = u >> 3;
        const int cc = u & 7;
        const unsigned short* src = wte + (size_t)rr * D_DIM + kt * 64 + cc * 8;
        __builtin_amdgcn_global_load_lds(
            (const __attribute__((address_space(1))) void*)src,
            (__attribute__((address_space(3))) void*)&lB[u * 8], 16, 0, 0);
      }
      __syncthreads();
#pragma unroll
      for (int kk = 0; kk < 2; ++kk) {
        const int e0 = kk * 32 + (lane >> 4) * 8;
        short8 a[4], b[4];
#pragma unroll
        for (int m = 0; m < 4; ++m) {
          const int r = wr * 64 + m * 16 + (lane & 15);
          a[m] = *reinterpret_cast<const short8*>(&lA[r * 64 + (e0 ^ ((r & 7) << 3))]);
        }
#pragma unroll
        for (int n = 0; n < 4; ++n) {
          const int r = wc * 64 + n * 16 + (lane & 15);
          b[n] = *reinterpret_cast<const short8*>(&lB[r * 64 + (e0 ^ ((r & 7) << 3))]);
        }
#pragma unroll
        for (int m = 0; m < 4; ++m)
#pragma unroll
          for (int n = 0; n < 4; ++n)
            acc[m][n] = __builtin_amdgcn_mfma_f32_16x16x32_bf16(a[m], b[n], acc[m][n], 0, 0, 0);
      }
    }
  }

#pragma unroll
  for (int m = 0; m < 4; ++m) {
#pragma unroll
    for (int n = 0; n < 4; ++n) {
      const int rbase = wr * 64 + m * 16 + ((lane >> 4) * 4);
      const int cl    = wc * 64 + n * 16 + (lane & 15);
#pragma unroll
      for (int reg = 0; reg < 4; ++reg) {
        const int r = rbase + reg;
        float bsum = 0.f;
#pragma unroll
        for (int e = 0; e < E_NUM; ++e) bsum += lG[r * 8 + e] * lBias[e * 128 + cl];
        out[(size_t)(m0 + r) * P_DIM + n0 + cl] = acc[m][n][reg] + bsum;
      }
    }
  }
}

// ============================ launch ============================

extern "C" void kernel_launch(void* const* d_in, const int* in_sizes, int n_in,
                              void* d_out, int out_size, void* d_ws, size_t ws_size,
                              hipStream_t stream) {
  const float* x  = (const float*)d_in[0];
  const float* gw = (const float*)d_in[1];
  const float* gb = (const float*)d_in[2];
  const float* ew = (const float*)d_in[3];
  const float* eb = (const float*)d_in[4];
  float* out = (float*)d_out;

  char* ws = (char*)d_ws;
  float* gate        = (float*)ws;                     // 256 KiB
  unsigned short* wt = (unsigned short*)(ws + 262144); // 16 MiB

  const size_t need_new = 262144ull + 16777216ull + 16777216ull;  // gate + wt + xb

  if (ws_size >= need_new) {
    unsigned short* xbb = (unsigned short*)(ws + 262144 + 16777216);  // 16 MiB
    wtrans2_kernel<<<dim3(D_DIM / 64, P_DIM / 64, E_NUM), 256, 0, stream>>>(ew, wt);
    prep_m_kernel<<<M_TOT / 4, 256, 0, stream>>>(x, gw, gb, eb, gate, xbb, out);
    gemm_ex2_kernel<<<1024, 256, 0, stream>>>(xbb, wt, gate, out);
  } else {
    gate_kernel<<<M_TOT / 4, 256, 0, stream>>>(x, gw, gb, gate);
    wtrans_kernel<<<dim3(D_DIM / 64, P_DIM / 64, E_NUM), 256, 0, stream>>>(ew, wt);
    moe_gemm_kernel<<<dim3(M_TOT / 128, P_DIM / 128), 256, 0, stream>>>(x, wt, gate, eb, out);
  }
}

// Round 16
// 193.243 us; speedup vs baseline: 1.3802x; 1.0002x over previous
//
#include <hip/hip_runtime.h>
#include <hip/hip_bf16.h>
#include <math.h>

#define M_TOT 8192
#define D_DIM 1024
#define E_NUM 8
#define P_DIM 1024
#define K_TOT (E_NUM * D_DIM)  // 8192

typedef __attribute__((ext_vector_type(8))) short short8;
typedef __attribute__((ext_vector_type(4))) float f32x4;
typedef __attribute__((ext_vector_type(8))) unsigned short u16x8;

// round-to-nearest-even f32 -> bf16 (finite inputs)
static __device__ __forceinline__ unsigned short f2bf(float f) {
  unsigned u = __builtin_bit_cast(unsigned, f);
  unsigned r = (u + 0x7fffu + ((u >> 16) & 1u)) >> 16;
  return (unsigned short)r;
}

// ---- fused prep: per row -> gate softmax + xb (bf16, swizzled) + out bias-init ----
__global__ __launch_bounds__(256) void prep_m_kernel(const float* __restrict__ x,
                                                     const float* __restrict__ gw,
                                                     const float* __restrict__ gb,
                                                     const float* __restrict__ eb,
                                                     float* __restrict__ gate,
                                                     unsigned short* __restrict__ xb,
                                                     float* __restrict__ out) {
  __shared__ __align__(16) unsigned short lx[4][1024];  // 8 KB
  const int wv   = threadIdx.x >> 6;
  const int lane = threadIdx.x & 63;
  const int row  = blockIdx.x * 4 + wv;
  const float* xr = x + (size_t)row * D_DIM;

  float acc[E_NUM];
#pragma unroll
  for (int e = 0; e < E_NUM; ++e) acc[e] = 0.f;
#pragma unroll
  for (int it = 0; it < 16; ++it) {
    const int d = it * 64 + lane;
    const float xv = xr[d];
    lx[wv][d] = f2bf(xv);
    const float4* g4 = reinterpret_cast<const float4*>(gw + (size_t)d * E_NUM);
    const float4 a = g4[0], b = g4[1];
    acc[0] += xv * a.x; acc[1] += xv * a.y; acc[2] += xv * a.z; acc[3] += xv * a.w;
    acc[4] += xv * b.x; acc[5] += xv * b.y; acc[6] += xv * b.z; acc[7] += xv * b.w;
  }
#pragma unroll
  for (int off = 32; off >= 1; off >>= 1) {
#pragma unroll
    for (int e = 0; e < E_NUM; ++e) acc[e] += __shfl_xor(acc[e], off, 64);
  }
  __syncthreads();  // publish LDS bf16 row

  float g[E_NUM], mx = -1e30f;
#pragma unroll
  for (int e = 0; e < E_NUM; ++e) { g[e] = acc[e] + gb[e]; mx = fmaxf(mx, g[e]); }
  float s = 0.f;
#pragma unroll
  for (int e = 0; e < E_NUM; ++e) { g[e] = expf(g[e] - mx); s += g[e]; }
  const float inv = 1.f / s;
#pragma unroll
  for (int e = 0; e < E_NUM; ++e) g[e] *= inv;
  if (lane == 0) {
#pragma unroll
    for (int e = 0; e < E_NUM; ++e) gate[(size_t)row * E_NUM + e] = g[e];
  }

  // xb: two swizzled 16B chunks per lane, sourced from LDS (contiguous)
  unsigned short* xrow = xb + (size_t)row * D_DIM;
#pragma unroll
  for (int h = 0; h < 2; ++h) {
    const int jd = lane * 2 + h;
    const int cbase = (jd >> 3) * 8 + ((jd & 7) ^ (row & 7));
    const u16x8 vv = *reinterpret_cast<const u16x8*>(&lx[wv][jd * 8]);
    *reinterpret_cast<u16x8*>(&xrow[cbase * 8]) = vv;
  }

  // bias-init: out[row][p] = sum_e g[e]*eb[e][p], coalesced float4 per lane
  float* orow = out + (size_t)row * P_DIM;
#pragma unroll
  for (int q = 0; q < 4; ++q) {
    const int p = q * 256 + lane * 4;
    float4 sv = {0.f, 0.f, 0.f, 0.f};
#pragma unroll
    for (int e = 0; e < E_NUM; ++e) {
      const float4 b4 = *reinterpret_cast<const float4*>(&eb[(size_t)e * P_DIM + p]);
      sv.x += g[e] * b4.x; sv.y += g[e] * b4.y; sv.z += g[e] * b4.z; sv.w += g[e] * b4.w;
    }
    *reinterpret_cast<float4*>(&orow[p]) = sv;
  }
}

// ---------------- W [E][D][P] f32 -> wt [P][E*D] bf16, swizzle baked per 64-short K-block ----------------
__global__ __launch_bounds__(256) void wtrans2_kernel(const float* __restrict__ w,
                                                      unsigned short* __restrict__ wt) {
  __shared__ float tile[64][65];
  const int e  = blockIdx.z;
  const int p0 = blockIdx.y * 64;
  const int d0 = blockIdx.x * 64;
  const int tx = threadIdx.x & 63;
  const int ty = threadIdx.x >> 6;
  const float* src = w + ((size_t)e * D_DIM + d0) * P_DIM + p0;
#pragma unroll
  for (int i = 0; i < 16; ++i) {
    const int dr = i * 4 + ty;
    tile[dr][tx] = src[(size_t)dr * P_DIM + tx];
  }
  __syncthreads();
#pragma unroll
  for (int i = 0; i < 16; ++i) {
    const int pr = i * 4 + ty;
    const int c = tx ^ ((pr & 7) << 3);  // involution, 16B-chunk granular
    wt[(size_t)(p0 + pr) * K_TOT + e * D_DIM + d0 + c] = f2bf(tile[tx][pr]);
  }
}

// ---- Horner-gated expert-loop GEMM: 128x128 tile, BK=64, 4 waves, split-K=2 over expert halves.
// __launch_bounds__(256,3): round-8's best-GEMM register-allocator config (151 us, MfmaUtil 42%).
__global__ __launch_bounds__(256, 3) void gemm_ex2_kernel(
    const unsigned short* __restrict__ xb,
    const unsigned short* __restrict__ wt,
    const float* __restrict__ gate,
    float* __restrict__ out) {
  __shared__ unsigned short lA[128 * 64];   // 16 KB
  __shared__ unsigned short lB[128 * 64];   // 16 KB
  __shared__ float lG[128 * 8];             // 4 KB  -> 36 KB total

  const int tid  = threadIdx.x;
  const int lane = tid & 63;
  const int wid  = tid >> 6;
  const int wr   = wid >> 1, wc = wid & 1;

  // 1024 blocks: xcd = bid&7 = nt (2MB wt slice L2-resident); idx: kh = idx&1, mt = idx>>1.
  const int bid = blockIdx.x;
  const int nt  = bid & 7;
  const int idx = bid >> 3;
  const int kh  = idx & 1;
  const int mt  = idx >> 1;
  const int m0  = mt * 128, n0 = nt * 128;

  reinterpret_cast<float4*>(lG)[tid] =
      reinterpret_cast<const float4*>(gate + (size_t)m0 * E_NUM)[tid];

  f32x4 acc[4][4];
#pragma unroll
  for (int i = 0; i < 4; ++i)
#pragma unroll
    for (int j = 0; j < 4; ++j)
#pragma unroll
      for (int k = 0; k < 4; ++k) acc[i][j][k] = 0.f;

  const int r0 = tid >> 3;  // 0..31
  const int c8 = tid & 7;   // 16B chunk within 64-short block
  const unsigned short* pAb = xb + (size_t)(m0 + r0) * D_DIM + c8 * 8;
  const unsigned short* pBb = wt + (size_t)(n0 + r0) * K_TOT + c8 * 8;

  for (int e = 0; e < 4; ++e) {
    const int eg = kh * 4 + e;
    if (e > 0) {
      // Horner rescale: acc *= g[row][eg-1] / g[row][eg]  (softmax gates bounded below, safe)
#pragma unroll
      for (int m = 0; m < 4; ++m) {
#pragma unroll
        for (int reg = 0; reg < 4; ++reg) {
          const int r = wr * 64 + m * 16 + (lane >> 4) * 4 + reg;
          const float ratio = lG[r * 8 + (eg - 1)] / lG[r * 8 + eg];
#pragma unroll
          for (int n = 0; n < 4; ++n) acc[m][n][reg] *= ratio;
        }
      }
    }
    const unsigned short* pB = pBb + (size_t)eg * D_DIM;
    for (int kt = 0; kt < 16; ++kt) {
      __syncthreads();  // previous tile's LDS reads complete
#pragma unroll
      for (int i = 0; i < 4; ++i) {
        __builtin_amdgcn_global_load_lds(
            (const __attribute__((address_space(1))) void*)(pAb + (size_t)i * 32 * D_DIM + kt * 64),
            (__attribute__((address_space(3))) void*)&lA[(tid + i * 256) * 8], 16, 0, 0);
      }
#pragma unroll
      for (int i = 0; i < 4; ++i) {
        __builtin_amdgcn_global_load_lds(
            (const __attribute__((address_space(1))) void*)(pB + (size_t)i * 32 * K_TOT + kt * 64),
            (__attribute__((address_space(3))) void*)&lB[(tid + i * 256) * 8], 16, 0, 0);
      }
      __syncthreads();  // compiler drains vmcnt before barrier
#pragma unroll
      for (int kk = 0; kk < 2; ++kk) {
        const int e0 = kk * 32 + (lane >> 4) * 8;
        short8 a[4], b[4];
#pragma unroll
        for (int m = 0; m < 4; ++m) {
          const int r = wr * 64 + m * 16 + (lane & 15);
          a[m] = *reinterpret_cast<const short8*>(&lA[r * 64 + (e0 ^ ((r & 7) << 3))]);
        }
#pragma unroll
        for (int n = 0; n < 4; ++n) {
          const int r = wc * 64 + n * 16 + (lane & 15);
          b[n] = *reinterpret_cast<const short8*>(&lB[r * 64 + (e0 ^ ((r & 7) << 3))]);
        }
#pragma unroll
        for (int m = 0; m < 4; ++m)
#pragma unroll
          for (int n = 0; n < 4; ++n)
            acc[m][n] = __builtin_amdgcn_mfma_f32_16x16x32_bf16(a[m], b[n], acc[m][n], 0, 0, 0);
      }
    }
  }

  // ---- epilogue: final Horner scale by g[row][kh*4+3]; atomic accumulate (bias pre-initialized) ----
#pragma unroll
  for (int n = 0; n < 4; ++n) {
    const int cl = wc * 64 + n * 16 + (lane & 15);
#pragma unroll
    for (int m = 0; m < 4; ++m) {
#pragma unroll
      for (int reg = 0; reg < 4; ++reg) {
        const int r  = wr * 64 + m * 16 + (lane >> 4) * 4 + reg;
        const float gl = lG[r * 8 + kh * 4 + 3];
        atomicAdd(&out[(size_t)(m0 + r) * P_DIM + n0 + cl], acc[m][n][reg] * gl);
      }
    }
  }
}

// ============================ FALLBACK PATH (round-2, passing) ============================

__global__ __launch_bounds__(256) void gate_kernel(const float* __restrict__ x,
                                                   const float* __restrict__ gw,
                                                   const float* __restrict__ gb,
                                                   float* __restrict__ gate) {
  const int row  = blockIdx.x * 4 + (threadIdx.x >> 6);
  const int lane = threadIdx.x & 63;
  const float* xr = x + (size_t)row * D_DIM;
  float acc[E_NUM];
#pragma unroll
  for (int e = 0; e < E_NUM; ++e) acc[e] = 0.f;
#pragma unroll
  for (int it = 0; it < 16; ++it) {
    const int d = it * 64 + lane;
    const float xv = xr[d];
    const float4* g4 = reinterpret_cast<const float4*>(gw + (size_t)d * E_NUM);
    float4 a = g4[0], b = g4[1];
    acc[0] += xv * a.x; acc[1] += xv * a.y; acc[2] += xv * a.z; acc[3] += xv * a.w;
    acc[4] += xv * b.x; acc[5] += xv * b.y; acc[6] += xv * b.z; acc[7] += xv * b.w;
  }
#pragma unroll
  for (int off = 32; off >= 1; off >>= 1) {
#pragma unroll
    for (int e = 0; e < E_NUM; ++e) acc[e] += __shfl_xor(acc[e], off, 64);
  }
  if (lane == 0) {
    float v[E_NUM], mx = -1e30f;
#pragma unroll
    for (int e = 0; e < E_NUM; ++e) { v[e] = acc[e] + gb[e]; mx = fmaxf(mx, v[e]); }
    float s = 0.f;
#pragma unroll
    for (int e = 0; e < E_NUM; ++e) { v[e] = expf(v[e] - mx); s += v[e]; }
    const float inv = 1.f / s;
#pragma unroll
    for (int e = 0; e < E_NUM; ++e) gate[(size_t)row * E_NUM + e] = v[e] * inv;
  }
}

__global__ __launch_bounds__(256) void wtrans_kernel(const float* __restrict__ w,
                                                     unsigned short* __restrict__ wt) {
  __shared__ float tile[64][65];
  const int e  = blockIdx.z;
  const int p0 = blockIdx.y * 64;
  const int d0 = blockIdx.x * 64;
  const int tx = threadIdx.x & 63;
  const int ty = threadIdx.x >> 6;
  const float* src = w + ((size_t)e * D_DIM + d0) * P_DIM + p0;
#pragma unroll
  for (int i = 0; i < 16; ++i) {
    const int dr = i * 4 + ty;
    tile[dr][tx] = src[(size_t)dr * P_DIM + tx];
  }
  __syncthreads();
  unsigned short* dst = wt + ((size_t)e * P_DIM + p0) * D_DIM + d0;
#pragma unroll
  for (int i = 0; i < 16; ++i) {
    const int pr = i * 4 + ty;
    const int cc = tx ^ ((pr & 7) << 3);
    dst[(size_t)pr * D_DIM + cc] = f2bf(tile[tx][pr]);
  }
}

__global__ __launch_bounds__(256, 2) void moe_gemm_kernel(
    const float* __restrict__ x,
    const unsigned short* __restrict__ wt,
    const float* __restrict__ gate,
    const float* __restrict__ eb,
    float* __restrict__ out) {
  __shared__ unsigned short lA[128 * 64];
  __shared__ unsigned short lB[128 * 64];
  __shared__ float lG[128 * 8];
  __shared__ float lBias[E_NUM * 128];

  const int tid  = threadIdx.x;
  const int lane = tid & 63;
  const int wid  = tid >> 6;
  const int wr   = wid >> 1, wc = wid & 1;
  const int m0   = blockIdx.x * 128;
  const int n0   = blockIdx.y * 128;

  reinterpret_cast<float4*>(lG)[tid] =
      reinterpret_cast<const float4*>(gate + (size_t)m0 * E_NUM)[tid];
  {
    const int e = tid >> 5, cc = (tid & 31) * 4;
    *reinterpret_cast<float4*>(&lBias[e * 128 + cc]) =
        *reinterpret_cast<const float4*>(&eb[(size_t)e * P_DIM + n0 + cc]);
  }
  __syncthreads();

  const int rA   = tid >> 1;
  const int colA = (tid & 1) * 32;
  const float* xrow = x + (size_t)(m0 + rA) * D_DIM + colA;

  f32x4 acc[4][4];
#pragma unroll
  for (int i = 0; i < 4; ++i)
#pragma unroll
    for (int jj = 0; jj < 4; ++jj)
#pragma unroll
      for (int k = 0; k < 4; ++k) acc[i][jj][k] = 0.f;

  for (int e = 0; e < E_NUM; ++e) {
    const float gs = lG[rA * 8 + e];
    const unsigned short* wte = wt + ((size_t)e * P_DIM + n0) * D_DIM;
    for (int kt = 0; kt < 16; ++kt) {
      __syncthreads();
      const float4* apv = reinterpret_cast<const float4*>(xrow + kt * 64);
#pragma unroll
      for (int jj = 0; jj < 4; ++jj) {
        float4 p = apv[2 * jj], q = apv[2 * jj + 1];
        u16x8 v;
        v[0] = f2bf(p.x * gs); v[1] = f2bf(p.y * gs);
        v[2] = f2bf(p.z * gs); v[3] = f2bf(p.w * gs);
        v[4] = f2bf(q.x * gs); v[5] = f2bf(q.y * gs);
        v[6] = f2bf(q.z * gs); v[7] = f2bf(q.w * gs);
        const int idxw = rA * 64 + ((colA + jj * 8) ^ ((rA & 7) << 3));
        *reinterpret_cast<u16x8*>(&lA[idxw]) = v;
      }
#pragma unroll
      for (int i = 0; i < 4; ++i) {
        const int u  = tid + i * 256;
        const int rr = u >> 3;
        const int cc = u & 7;
        const unsigned short* src = wte + (size_t)rr * D_DIM + kt * 64 + cc * 8;
        __builtin_amdgcn_global_load_lds(
            (const __attribute__((address_space(1))) void*)src,
            (__attribute__((address_space(3))) void*)&lB[u * 8], 16, 0, 0);
      }
      __syncthreads();
#pragma unroll
      for (int kk = 0; kk < 2; ++kk) {
        const int e0 = kk * 32 + (lane >> 4) * 8;
        short8 a[4], b[4];
#pragma unroll
        for (int m = 0; m < 4; ++m) {
          const int r = wr * 64 + m * 16 + (lane & 15);
          a[m] = *reinterpret_cast<const short8*>(&lA[r * 64 + (e0 ^ ((r & 7) << 3))]);
        }
#pragma unroll
        for (int n = 0; n < 4; ++n) {
          const int r = wc * 64 + n * 16 + (lane & 15);
          b[n] = *reinterpret_cast<const short8*>(&lB[r * 64 + (e0 ^ ((r & 7) << 3))]);
        }
#pragma unroll
        for (int m = 0; m < 4; ++m)
#pragma unroll
          for (int n = 0; n < 4; ++n)
            acc[m][n] = __builtin_amdgcn_mfma_f32_16x16x32_bf16(a[m], b[n], acc[m][n], 0, 0, 0);
      }
    }
  }

#pragma unroll
  for (int m = 0; m < 4; ++m) {
#pragma unroll
    for (int n = 0; n < 4; ++n) {
      const int rbase = wr * 64 + m * 16 + ((lane >> 4) * 4);
      const int cl    = wc * 64 + n * 16 + (lane & 15);
#pragma unroll
      for (int reg = 0; reg < 4; ++reg) {
        const int r = rbase + reg;
        float bsum = 0.f;
#pragma unroll
        for (int e = 0; e < E_NUM; ++e) bsum += lG[r * 8 + e] * lBias[e * 128 + cl];
        out[(size_t)(m0 + r) * P_DIM + n0 + cl] = acc[m][n][reg] + bsum;
      }
    }
  }
}

// ============================ launch ============================

extern "C" void kernel_launch(void* const* d_in, const int* in_sizes, int n_in,
                              void* d_out, int out_size, void* d_ws, size_t ws_size,
                              hipStream_t stream) {
  const float* x  = (const float*)d_in[0];
  const float* gw = (const float*)d_in[1];
  const float* gb = (const float*)d_in[2];
  const float* ew = (const float*)d_in[3];
  const float* eb = (const float*)d_in[4];
  float* out = (float*)d_out;

  char* ws = (char*)d_ws;
  float* gate        = (float*)ws;                     // 256 KiB
  unsigned short* wt = (unsigned short*)(ws + 262144); // 16 MiB

  const size_t need_new = 262144ull + 16777216ull + 16777216ull;  // gate + wt + xb

  if (ws_size >= need_new) {
    unsigned short* xbb = (unsigned short*)(ws + 262144 + 16777216);  // 16 MiB
    wtrans2_kernel<<<dim3(D_DIM / 64, P_DIM / 64, E_NUM), 256, 0, stream>>>(ew, wt);
    prep_m_kernel<<<M_TOT / 4, 256, 0, stream>>>(x, gw, gb, eb, gate, xbb, out);
    gemm_ex2_kernel<<<1024, 256, 0, stream>>>(xbb, wt, gate, out);
  } else {
    gate_kernel<<<M_TOT / 4, 256, 0, stream>>>(x, gw, gb, gate);
    wtrans_kernel<<<dim3(D_DIM / 64, P_DIM / 64, E_NUM), 256, 0, stream>>>(ew, wt);
    moe_gemm_kernel<<<dim3(M_TOT / 128, P_DIM / 128), 256, 0, stream>>>(x, wt, gate, eb, out);
  }
}

// Round 17
// 188.845 us; speedup vs baseline: 1.4123x; 1.0233x over previous
//
#include <hip/hip_runtime.h>
#include <hip/hip_bf16.h>
#include <math.h>

#define M_TOT 8192
#define D_DIM 1024
#define E_NUM 8
#define P_DIM 1024
#define K_TOT (E_NUM * D_DIM)  // 8192

typedef __attribute__((ext_vector_type(8))) short short8;
typedef __attribute__((ext_vector_type(4))) float f32x4;
typedef __attribute__((ext_vector_type(8))) unsigned short u16x8;

// round-to-nearest-even f32 -> bf16 (finite inputs)
static __device__ __forceinline__ unsigned short f2bf(float f) {
  unsigned u = __builtin_bit_cast(unsigned, f);
  unsigned r = (u + 0x7fffu + ((u >> 16) & 1u)) >> 16;
  return (unsigned short)r;
}

// ---- merged prep: blocks [0,2048) = per-row gate+xb+bias-init; [2048,4096) = W-transpose tiles ----
__global__ __launch_bounds__(256) void prep_all_kernel(const float* __restrict__ x,
                                                       const float* __restrict__ gw,
                                                       const float* __restrict__ gb,
                                                       const float* __restrict__ ew,
                                                       const float* __restrict__ eb,
                                                       float* __restrict__ gate,
                                                       unsigned short* __restrict__ xb,
                                                       unsigned short* __restrict__ wt,
                                                       float* __restrict__ out) {
  __shared__ __align__(16) unsigned short lx[4][1024];  // 8 KB   (prep path)
  __shared__ float tile[64][65];                        // 16.25 KB (wtrans path)

  if (blockIdx.x < 2048) {
    // ================= per-row prep (round-15/16 verified path) =================
    const int wv   = threadIdx.x >> 6;
    const int lane = threadIdx.x & 63;
    const int row  = blockIdx.x * 4 + wv;
    const float* xr = x + (size_t)row * D_DIM;

    float acc[E_NUM];
#pragma unroll
    for (int e = 0; e < E_NUM; ++e) acc[e] = 0.f;
#pragma unroll
    for (int it = 0; it < 16; ++it) {
      const int d = it * 64 + lane;
      const float xv = xr[d];
      lx[wv][d] = f2bf(xv);
      const float4* g4 = reinterpret_cast<const float4*>(gw + (size_t)d * E_NUM);
      const float4 a = g4[0], b = g4[1];
      acc[0] += xv * a.x; acc[1] += xv * a.y; acc[2] += xv * a.z; acc[3] += xv * a.w;
      acc[4] += xv * b.x; acc[5] += xv * b.y; acc[6] += xv * b.z; acc[7] += xv * b.w;
    }
#pragma unroll
    for (int off = 32; off >= 1; off >>= 1) {
#pragma unroll
      for (int e = 0; e < E_NUM; ++e) acc[e] += __shfl_xor(acc[e], off, 64);
    }
    __syncthreads();  // publish LDS bf16 row

    float g[E_NUM], mx = -1e30f;
#pragma unroll
    for (int e = 0; e < E_NUM; ++e) { g[e] = acc[e] + gb[e]; mx = fmaxf(mx, g[e]); }
    float s = 0.f;
#pragma unroll
    for (int e = 0; e < E_NUM; ++e) { g[e] = expf(g[e] - mx); s += g[e]; }
    const float inv = 1.f / s;
#pragma unroll
    for (int e = 0; e < E_NUM; ++e) g[e] *= inv;
    if (lane == 0) {
#pragma unroll
      for (int e = 0; e < E_NUM; ++e) gate[(size_t)row * E_NUM + e] = g[e];
    }

    // xb: two swizzled 16B chunks per lane, sourced from LDS (contiguous)
    unsigned short* xrow = xb + (size_t)row * D_DIM;
#pragma unroll
    for (int h = 0; h < 2; ++h) {
      const int jd = lane * 2 + h;
      const int cbase = (jd >> 3) * 8 + ((jd & 7) ^ (row & 7));
      const u16x8 vv = *reinterpret_cast<const u16x8*>(&lx[wv][jd * 8]);
      *reinterpret_cast<u16x8*>(&xrow[cbase * 8]) = vv;
    }

    // bias-init: out[row][p] = sum_e g[e]*eb[e][p], coalesced float4 per lane
    float* orow = out + (size_t)row * P_DIM;
#pragma unroll
    for (int q = 0; q < 4; ++q) {
      const int p = q * 256 + lane * 4;
      float4 sv = {0.f, 0.f, 0.f, 0.f};
#pragma unroll
      for (int e = 0; e < E_NUM; ++e) {
        const float4 b4 = *reinterpret_cast<const float4*>(&eb[(size_t)e * P_DIM + p]);
        sv.x += g[e] * b4.x; sv.y += g[e] * b4.y; sv.z += g[e] * b4.z; sv.w += g[e] * b4.w;
      }
      *reinterpret_cast<float4*>(&orow[p]) = sv;
    }
  } else {
    // ================= W [E][D][P] f32 -> wt [P][E*D] bf16, swizzle baked =================
    const int bid2 = blockIdx.x - 2048;            // 0..2047 = d0idx + 16*p0idx + 256*e
    const int e  = bid2 >> 8;
    const int p0 = ((bid2 >> 4) & 15) * 64;
    const int d0 = (bid2 & 15) * 64;
    const int tx = threadIdx.x & 63;
    const int ty = threadIdx.x >> 6;
    const float* src = ew + ((size_t)e * D_DIM + d0) * P_DIM + p0;
#pragma unroll
    for (int i = 0; i < 16; ++i) {
      const int dr = i * 4 + ty;
      tile[dr][tx] = src[(size_t)dr * P_DIM + tx];
    }
    __syncthreads();
    // vectorized swizzled stores: 512 (pr,chunk) pairs, one u16x8 each.
    // chunk a -> a ^ (pr&7), elements in order (identical mapping to scalar version).
#pragma unroll
    for (int h = 0; h < 2; ++h) {
      const int u  = threadIdx.x + h * 256;  // 0..511
      const int pr = u >> 3;                 // 0..63
      const int ch = u & 7;                  // source chunk
      u16x8 v;
#pragma unroll
      for (int j = 0; j < 8; ++j) v[j] = f2bf(tile[ch * 8 + j][pr]);
      const int cs = ch ^ (pr & 7);
      *reinterpret_cast<u16x8*>(&wt[(size_t)(p0 + pr) * K_TOT + e * D_DIM + d0 + cs * 8]) = v;
    }
  }
}

// ---- Horner-gated expert-loop GEMM: 128x128 tile, BK=64, 4 waves, split-K=2 over expert halves ----
__global__ __launch_bounds__(256, 3) void gemm_ex2_kernel(
    const unsigned short* __restrict__ xb,
    const unsigned short* __restrict__ wt,
    const float* __restrict__ gate,
    float* __restrict__ out) {
  __shared__ unsigned short lA[128 * 64];   // 16 KB
  __shared__ unsigned short lB[128 * 64];   // 16 KB
  __shared__ float lG[128 * 8];             // 4 KB  -> 36 KB total

  const int tid  = threadIdx.x;
  const int lane = tid & 63;
  const int wid  = tid >> 6;
  const int wr   = wid >> 1, wc = wid & 1;

  // 1024 blocks: xcd = bid&7 = nt (2MB wt slice L2-resident); idx: kh = idx&1, mt = idx>>1.
  const int bid = blockIdx.x;
  const int nt  = bid & 7;
  const int idx = bid >> 3;
  const int kh  = idx & 1;
  const int mt  = idx >> 1;
  const int m0  = mt * 128, n0 = nt * 128;

  reinterpret_cast<float4*>(lG)[tid] =
      reinterpret_cast<const float4*>(gate + (size_t)m0 * E_NUM)[tid];

  f32x4 acc[4][4];
#pragma unroll
  for (int i = 0; i < 4; ++i)
#pragma unroll
    for (int j = 0; j < 4; ++j)
#pragma unroll
      for (int k = 0; k < 4; ++k) acc[i][j][k] = 0.f;

  const int r0 = tid >> 3;  // 0..31
  const int c8 = tid & 7;   // 16B chunk within 64-short block
  const unsigned short* pAb = xb + (size_t)(m0 + r0) * D_DIM + c8 * 8;
  const unsigned short* pBb = wt + (size_t)(n0 + r0) * K_TOT + c8 * 8;

  for (int e = 0; e < 4; ++e) {
    const int eg = kh * 4 + e;
    if (e > 0) {
      // Horner rescale: acc *= g[row][eg-1] / g[row][eg]  (softmax gates bounded below, safe)
#pragma unroll
      for (int m = 0; m < 4; ++m) {
#pragma unroll
        for (int reg = 0; reg < 4; ++reg) {
          const int r = wr * 64 + m * 16 + (lane >> 4) * 4 + reg;
          const float ratio = lG[r * 8 + (eg - 1)] / lG[r * 8 + eg];
#pragma unroll
          for (int n = 0; n < 4; ++n) acc[m][n][reg] *= ratio;
        }
      }
    }
    const unsigned short* pB = pBb + (size_t)eg * D_DIM;
    for (int kt = 0; kt < 16; ++kt) {
      __syncthreads();  // previous tile's LDS reads complete
#pragma unroll
      for (int i = 0; i < 4; ++i) {
        __builtin_amdgcn_global_load_lds(
            (const __attribute__((address_space(1))) void*)(pAb + (size_t)i * 32 * D_DIM + kt * 64),
            (__attribute__((address_space(3))) void*)&lA[(tid + i * 256) * 8], 16, 0, 0);
      }
#pragma unroll
      for (int i = 0; i < 4; ++i) {
        __builtin_amdgcn_global_load_lds(
            (const __attribute__((address_space(1))) void*)(pB + (size_t)i * 32 * K_TOT + kt * 64),
            (__attribute__((address_space(3))) void*)&lB[(tid + i * 256) * 8], 16, 0, 0);
      }
      __syncthreads();  // compiler drains vmcnt before barrier
#pragma unroll
      for (int kk = 0; kk < 2; ++kk) {
        const int e0 = kk * 32 + (lane >> 4) * 8;
        short8 a[4], b[4];
#pragma unroll
        for (int m = 0; m < 4; ++m) {
          const int r = wr * 64 + m * 16 + (lane & 15);
          a[m] = *reinterpret_cast<const short8*>(&lA[r * 64 + (e0 ^ ((r & 7) << 3))]);
        }
#pragma unroll
        for (int n = 0; n < 4; ++n) {
          const int r = wc * 64 + n * 16 + (lane & 15);
          b[n] = *reinterpret_cast<const short8*>(&lB[r * 64 + (e0 ^ ((r & 7) << 3))]);
        }
#pragma unroll
        for (int m = 0; m < 4; ++m)
#pragma unroll
          for (int n = 0; n < 4; ++n)
            acc[m][n] = __builtin_amdgcn_mfma_f32_16x16x32_bf16(a[m], b[n], acc[m][n], 0, 0, 0);
      }
    }
  }

  // ---- epilogue: final Horner scale by g[row][kh*4+3]; atomic accumulate (bias pre-initialized) ----
#pragma unroll
  for (int n = 0; n < 4; ++n) {
    const int cl = wc * 64 + n * 16 + (lane & 15);
#pragma unroll
    for (int m = 0; m < 4; ++m) {
#pragma unroll
      for (int reg = 0; reg < 4; ++reg) {
        const int r  = wr * 64 + m * 16 + (lane >> 4) * 4 + reg;
        const float gl = lG[r * 8 + kh * 4 + 3];
        atomicAdd(&out[(size_t)(m0 + r) * P_DIM + n0 + cl], acc[m][n][reg] * gl);
      }
    }
  }
}

// ============================ FALLBACK PATH (round-2, passing) ============================

__global__ __launch_bounds__(256) void gate_kernel(const float* __restrict__ x,
                                                   const float* __restrict__ gw,
                                                   const float* __restrict__ gb,
                                                   float* __restrict__ gate) {
  const int row  = blockIdx.x * 4 + (threadIdx.x >> 6);
  const int lane = threadIdx.x & 63;
  const float* xr = x + (size_t)row * D_DIM;
  float acc[E_NUM];
#pragma unroll
  for (int e = 0; e < E_NUM; ++e) acc[e] = 0.f;
#pragma unroll
  for (int it = 0; it < 16; ++it) {
    const int d = it * 64 + lane;
    const float xv = xr[d];
    const float4* g4 = reinterpret_cast<const float4*>(gw + (size_t)d * E_NUM);
    float4 a = g4[0], b = g4[1];
    acc[0] += xv * a.x; acc[1] += xv * a.y; acc[2] += xv * a.z; acc[3] += xv * a.w;
    acc[4] += xv * b.x; acc[5] += xv * b.y; acc[6] += xv * b.z; acc[7] += xv * b.w;
  }
#pragma unroll
  for (int off = 32; off >= 1; off >>= 1) {
#pragma unroll
    for (int e = 0; e < E_NUM; ++e) acc[e] += __shfl_xor(acc[e], off, 64);
  }
  if (lane == 0) {
    float v[E_NUM], mx = -1e30f;
#pragma unroll
    for (int e = 0; e < E_NUM; ++e) { v[e] = acc[e] + gb[e]; mx = fmaxf(mx, v[e]); }
    float s = 0.f;
#pragma unroll
    for (int e = 0; e < E_NUM; ++e) { v[e] = expf(v[e] - mx); s += v[e]; }
    const float inv = 1.f / s;
#pragma unroll
    for (int e = 0; e < E_NUM; ++e) gate[(size_t)row * E_NUM + e] = v[e] * inv;
  }
}

__global__ __launch_bounds__(256) void wtrans_kernel(const float* __restrict__ w,
                                                     unsigned short* __restrict__ wt) {
  __shared__ float tile[64][65];
  const int e  = blockIdx.z;
  const int p0 = blockIdx.y * 64;
  const int d0 = blockIdx.x * 64;
  const int tx = threadIdx.x & 63;
  const int ty = threadIdx.x >> 6;
  const float* src = w + ((size_t)e * D_DIM + d0) * P_DIM + p0;
#pragma unroll
  for (int i = 0; i < 16; ++i) {
    const int dr = i * 4 + ty;
    tile[dr][tx] = src[(size_t)dr * P_DIM + tx];
  }
  __syncthreads();
  unsigned short* dst = wt + ((size_t)e * P_DIM + p0) * D_DIM + d0;
#pragma unroll
  for (int i = 0; i < 16; ++i) {
    const int pr = i * 4 + ty;
    const int cc = tx ^ ((pr & 7) << 3);
    dst[(size_t)pr * D_DIM + cc] = f2bf(tile[tx][pr]);
  }
}

__global__ __launch_bounds__(256, 2) void moe_gemm_kernel(
    const float* __restrict__ x,
    const unsigned short* __restrict__ wt,
    const float* __restrict__ gate,
    const float* __restrict__ eb,
    float* __restrict__ out) {
  __shared__ unsigned short lA[128 * 64];
  __shared__ unsigned short lB[128 * 64];
  __shared__ float lG[128 * 8];
  __shared__ float lBias[E_NUM * 128];

  const int tid  = threadIdx.x;
  const int lane = tid & 63;
  const int wid  = tid >> 6;
  const int wr   = wid >> 1, wc = wid & 1;
  const int m0   = blockIdx.x * 128;
  const int n0   = blockIdx.y * 128;

  reinterpret_cast<float4*>(lG)[tid] =
      reinterpret_cast<const float4*>(gate + (size_t)m0 * E_NUM)[tid];
  {
    const int e = tid >> 5, cc = (tid & 31) * 4;
    *reinterpret_cast<float4*>(&lBias[e * 128 + cc]) =
        *reinterpret_cast<const float4*>(&eb[(size_t)e * P_DIM + n0 + cc]);
  }
  __syncthreads();

  const int rA   = tid >> 1;
  const int colA = (tid & 1) * 32;
  const float* xrow = x + (size_t)(m0 + rA) * D_DIM + colA;

  f32x4 acc[4][4];
#pragma unroll
  for (int i = 0; i < 4; ++i)
#pragma unroll
    for (int jj = 0; jj < 4; ++jj)
#pragma unroll
      for (int k = 0; k < 4; ++k) acc[i][jj][k] = 0.f;

  for (int e = 0; e < E_NUM; ++e) {
    const float gs = lG[rA * 8 + e];
    const unsigned short* wte = wt + ((size_t)e * P_DIM + n0) * D_DIM;
    for (int kt = 0; kt < 16; ++kt) {
      __syncthreads();
      const float4* apv = reinterpret_cast<const float4*>(xrow + kt * 64);
#pragma unroll
      for (int jj = 0; jj < 4; ++jj) {
        float4 p = apv[2 * jj], q = apv[2 * jj + 1];
        u16x8 v;
        v[0] = f2bf(p.x * gs); v[1] = f2bf(p.y * gs);
        v[2] = f2bf(p.z * gs); v[3] = f2bf(p.w * gs);
        v[4] = f2bf(q.x * gs); v[5] = f2bf(q.y * gs);
        v[6] = f2bf(q.z * gs); v[7] = f2bf(q.w * gs);
        const int idxw = rA * 64 + ((colA + jj * 8) ^ ((rA & 7) << 3));
        *reinterpret_cast<u16x8*>(&lA[idxw]) = v;
      }
#pragma unroll
      for (int i = 0; i < 4; ++i) {
        const int u  = tid + i * 256;
        const int rr = u >> 3;
        const int cc = u & 7;
        const unsigned short* src = wte + (size_t)rr * D_DIM + kt * 64 + cc * 8;
        __builtin_amdgcn_global_load_lds(
            (const __attribute__((address_space(1))) void*)src,
            (__attribute__((address_space(3))) void*)&lB[u * 8], 16, 0, 0);
      }
      __syncthreads();
#pragma unroll
      for (int kk = 0; kk < 2; ++kk) {
        const int e0 = kk * 32 + (lane >> 4) * 8;
        short8 a[4], b[4];
#pragma unroll
        for (int m = 0; m < 4; ++m) {
          const int r = wr * 64 + m * 16 + (lane & 15);
          a[m] = *reinterpret_cast<const short8*>(&lA[r * 64 + (e0 ^ ((r & 7) << 3))]);
        }
#pragma unroll
        for (int n = 0; n < 4; ++n) {
          const int r = wc * 64 + n * 16 + (lane & 15);
          b[n] = *reinterpret_cast<const short8*>(&lB[r * 64 + (e0 ^ ((r & 7) << 3))]);
        }
#pragma unroll
        for (int m = 0; m < 4; ++m)
#pragma unroll
          for (int n = 0; n < 4; ++n)
            acc[m][n] = __builtin_amdgcn_mfma_f32_16x16x32_bf16(a[m], b[n], acc[m][n], 0, 0, 0);
      }
    }
  }

#pragma unroll
  for (int m = 0; m < 4; ++m) {
#pragma unroll
    for (int n = 0; n < 4; ++n) {
      const int rbase = wr * 64 + m * 16 + ((lane >> 4) * 4);
      const int cl    = wc * 64 + n * 16 + (lane & 15);
#pragma unroll
      for (int reg = 0; reg < 4; ++reg) {
        const int r = rbase + reg;
        float bsum = 0.f;
#pragma unroll
        for (int e = 0; e < E_NUM; ++e) bsum += lG[r * 8 + e] * lBias[e * 128 + cl];
        out[(size_t)(m0 + r) * P_DIM + n0 + cl] = acc[m][n][reg] + bsum;
      }
    }
  }
}

// ============================ launch ============================

extern "C" void kernel_launch(void* const* d_in, const int* in_sizes, int n_in,
                              void* d_out, int out_size, void* d_ws, size_t ws_size,
                              hipStream_t stream) {
  const float* x  = (const float*)d_in[0];
  const float* gw = (const float*)d_in[1];
  const float* gb = (const float*)d_in[2];
  const float* ew = (const float*)d_in[3];
  const float* eb = (const float*)d_in[4];
  float* out = (float*)d_out;

  char* ws = (char*)d_ws;
  float* gate        = (float*)ws;                     // 256 KiB
  unsigned short* wt = (unsigned short*)(ws + 262144); // 16 MiB

  const size_t need_new = 262144ull + 16777216ull + 16777216ull;  // gate + wt + xb

  if (ws_size >= need_new) {
    unsigned short* xbb = (unsigned short*)(ws + 262144 + 16777216);  // 16 MiB
    prep_all_kernel<<<4096, 256, 0, stream>>>(x, gw, gb, ew, eb, gate, xbb, wt, out);
    gemm_ex2_kernel<<<1024, 256, 0, stream>>>(xbb, wt, gate, out);
  } else {
    gate_kernel<<<M_TOT / 4, 256, 0, stream>>>(x, gw, gb, gate);
    wtrans_kernel<<<dim3(D_DIM / 64, P_DIM / 64, E_NUM), 256, 0, stream>>>(ew, wt);
    moe_gemm_kernel<<<dim3(M_TOT / 128, P_DIM / 128), 256, 0, stream>>>(x, wt, gate, eb, out);
  }
}